// Round 8
// baseline (291.548 us; speedup 1.0000x reference)
//
#include <hip/hip_runtime.h>
#include <math.h>

#define KN 16
#define DM 256
#define NS 3
#define NE 120
#define NT_TRI 560
#define NBATCH 512
#define TAUF 1e-4f
#define KAUG 1664            // 1536 + 6 bias cols + 122 zero pad (13*128)

typedef unsigned short ushort_t;
typedef __attribute__((ext_vector_type(8))) short short8v;
typedef __attribute__((ext_vector_type(4))) short short4v;
typedef __attribute__((ext_vector_type(4))) float f32x4;

// ---- workspace byte offsets (~39 MB total) ----
#define OFF_WSTACK 0u          // bf16 [256][1664]                       851968
#define OFF_WF1T   851968u     // bf16 [1024][256]                       524288
#define OFF_WF2T   1376256u    // bf16 [256][1024]                       524288
#define OFF_TOPO   1900544u    // f32 Q/P2/adj[768]; midOff[17]; triSrt[560]
#define OFF_RST    1908736u    // f32 [512][96]                         196608
#define OFF_TBF    2105344u    // bf16 [512][6][16][32]                3145728
#define OFF_XNT    5251072u    // bf16 [512][256][32]                  8388608
#define OFF_Z      13639680u   // bf16 [8192][1664]                   27262976
#define OFF_H      13639680u   // bf16 [8192][1024] aliases Z

__device__ __forceinline__ ushort_t f2bf(float f) {
    union { float f; unsigned int u; } v; v.f = f;
    unsigned int r = v.u + 0x7FFFu + ((v.u >> 16) & 1u);
    return (ushort_t)(r >> 16);
}
__device__ __forceinline__ void gload_lds16(const void* g, void* l) {
    auto gp = (const __attribute__((address_space(1))) unsigned int*)(unsigned long long)(g);
    auto lp = (__attribute__((address_space(3))) unsigned int*)(unsigned long long)(l);
    __builtin_amdgcn_global_load_lds(gp, lp, 16, 0, 0);
}

// ---------------------------------------------------------------------------
// Prep: bid<102 fuse Wv0/We x Wout -> Wstack ; bid<166 T(Wf1) ; bid<230 T(Wf2)
//       bid==230 topology tables (Q,P2,adj + mid-sorted triangle buckets)
// ---------------------------------------------------------------------------
__global__ __launch_bounds__(256) void prep_kernel(
    const float* __restrict__ Wv0, const float* __restrict__ bv0,
    const float* __restrict__ We,  const float* __restrict__ be,
    const float* __restrict__ Wout,
    const float* __restrict__ Wf1, const float* __restrict__ Wf2,
    const int* __restrict__ e_i, const int* __restrict__ e_j,
    const int* __restrict__ t_ij, const int* __restrict__ t_jk, const int* __restrict__ t_ik,
    ushort_t* __restrict__ wstack, ushort_t* __restrict__ wf1t,
    ushort_t* __restrict__ wf2t,
    float* __restrict__ topoF, int* __restrict__ midOff, int* __restrict__ triSrt)
{
    __shared__ float lhs[16][DM];
    __shared__ float tile[64][65];
    __shared__ int   eidxL[256];
    __shared__ int   cnts[16], offs[17];
    const int bid = blockIdx.x;
    const int j = threadIdx.x;

    if (bid == 230) {   // topology tables
        eidxL[j] = -1;
        __syncthreads();
        if (j < NE) {
            const int i = e_i[j], jn = e_j[j];
            eidxL[i*16 + jn] = j; eidxL[jn*16 + i] = j;
        }
        __syncthreads();
        const int n = j >> 4, m = j & 15;
        float q, p2, adj;
        if (n != m) {
            const int e = eidxL[j];
            if (e >= 0) { q = (m == e_j[e]) ? 1.f : -1.f; p2 = 1.f; adj = 1.f; }
            else        { q = 0.f; p2 = 0.f; adj = 0.f; }
        } else {
            q = 0.f; p2 = 0.f; adj = 0.f;
            for (int kk = 0; kk < KN; ++kk) {
                if (kk == n) continue;
                const int e = eidxL[n*16 + kk];
                if (e >= 0) { q += (n == e_j[e]) ? 1.f : -1.f; p2 += 1.f; }
            }
        }
        topoF[j] = q; topoF[256 + j] = p2; topoF[512 + j] = adj;

        // mid-sorted triangle buckets (deterministic)
        if (j < 16) {
            int c = 0;
            for (int tt = 0; tt < NT_TRI; ++tt) {
                const int eij = t_ij[tt], ejk = t_jk[tt];
                const int a0 = e_i[eij], a1 = e_j[eij];
                const int b0 = e_i[ejk];
                const int mid = (b0 == a0 || b0 == a1) ? b0 : e_j[ejk];
                if (mid == j) ++c;
            }
            cnts[j] = c;
        }
        __syncthreads();
        if (j == 0) {
            int s = 0;
            for (int q2 = 0; q2 < 16; ++q2) { offs[q2] = s; s += cnts[q2]; }
            offs[16] = s;
        }
        __syncthreads();
        if (j < 17) midOff[j] = offs[j];
        if (j < 16) {
            int w = offs[j];
            for (int tt = 0; tt < NT_TRI; ++tt) {
                const int eij = t_ij[tt], ejk = t_jk[tt], eik = t_ik[tt];
                const int a0 = e_i[eij], a1 = e_j[eij];
                const int b0 = e_i[ejk], b1v = e_j[ejk];
                const int c0 = e_i[eik], c1 = e_j[eik];
                const int mid = (b0 == a0 || b0 == a1) ? b0 : b1v;
                if (mid == j) {
                    const int ia = a0*16 + a1, ib = b0*16 + b1v, ic = c0*16 + c1;
                    triSrt[w++] = ia | (ib << 8) | (ic << 16);
                }
            }
        }
        return;
    }

    if (bid < 102) {
        const int m = bid / 17, by = bid % 17;
        const int path = m / 3, s = m % 3;
        const float* __restrict__ Wo = Wout + (size_t)m*DM*DM;
        if (by == 16) {   // fused bias -> K-row 1536+m ; zero pad K-rows
            const float* bv = (path == 0) ? bv0 : be;
            const float f = (path == 0) ? 1.0f : 0.5f;   // 1_E = 0.5*|B1|^T 1_K
            float acc = 0.f;
            for (int k = 0; k < DM; ++k)
                acc += bv[s*DM + k] * f * Wo[k*DM + j];
            wstack[(size_t)j*KAUG + 1536 + m] = f2bf(acc);
            if (m == 0)
                for (int c = 1542; c < KAUG; ++c)
                    wstack[(size_t)j*KAUG + c] = 0;
            return;
        }
        const float* src = (path == 0) ? Wv0 : We;
        const int i0 = by * 16;
        for (int r = 0; r < 16; ++r)
            lhs[r][j] = src[(size_t)(i0 + r)*(NS*DM) + s*DM + j];
        __syncthreads();
        float acc[16];
#pragma unroll
        for (int r = 0; r < 16; ++r) acc[r] = 0.f;
        for (int k = 0; k < DM; ++k) {
            const float w = Wo[k*DM + j];
#pragma unroll
            for (int r = 0; r < 16; ++r) acc[r] += lhs[r][k] * w;
        }
#pragma unroll
        for (int r = 0; r < 16; ++r)
            wstack[(size_t)j*KAUG + m*DM + i0 + r] = f2bf(acc[r]);
        return;
    }

    // transpose branches
    const float* in; ushort_t* outp; int R, C, rt, ct;
    if (bid < 166) {
        const int q = bid - 102;
        in = Wf1; outp = wf1t; R = 256; C = 1024;
        rt = (q >> 4) * 64; ct = (q & 15) * 64;
    } else {
        const int q = bid - 166;
        in = Wf2; outp = wf2t; R = 1024; C = 256;
        rt = (q >> 2) * 64; ct = (q & 3) * 64;
    }
#pragma unroll
    for (int q2 = 0; q2 < 16; ++q2) {
        const int idx = q2*256 + j;
        const int r = idx >> 6, c = idx & 63;
        tile[r][c] = in[(size_t)(rt + r)*C + ct + c];
    }
    __syncthreads();
#pragma unroll
    for (int q2 = 0; q2 < 16; ++q2) {
        const int idx = q2*256 + j;
        const int cc = idx >> 6, rr = idx & 63;
        outp[(size_t)(ct + cc)*R + rt + rr] = f2bf(tile[rr][cc]);
    }
}

// ---------------------------------------------------------------------------
// Topo kernel: LN -> P -> A_s -> T (atomic-free tri pass). Dumps Tbf, xnT,
// rowsums to workspace. One block per batch.
// ---------------------------------------------------------------------------
__global__ __launch_bounds__(256) void topo_kernel(
    const float* __restrict__ x, const float* __restrict__ mask,
    const float* __restrict__ log_scales,
    const float* __restrict__ Wg, const float* __restrict__ bg,
    const float* __restrict__ g1, const float* __restrict__ b1,
    const float* __restrict__ topoF, const int* __restrict__ midOff,
    const int* __restrict__ triSrt,
    ushort_t* __restrict__ tbf, ushort_t* __restrict__ xnt,
    float* __restrict__ rstOut)
{
    const int b = blockIdx.x;
    const int t = threadIdx.x;
    const int n = t >> 4, m = t & 15;

    __shared__ ushort_t xnbT[DM][32];    // xn^T [col][node], cols 16..31 = 0 (16 KB)
    __shared__ float Plds[KN][KN];
    __shared__ float mskL[KN];
    __shared__ float QL[256];
    __shared__ float P2L[256];
    __shared__ float adjL[256];
    __shared__ float sA[NS][KN][KN];
    __shared__ float part[4][NS][KN];
    __shared__ ushort_t Tbf[6][KN][32];  // K padded to 32, 6 KB

    // ---- phase 0: tables, mask, LN, P ----
    QL[t]  = topoF[t];
    P2L[t] = topoF[256 + t];
    adjL[t] = topoF[512 + t];
    if (t < KN) mskL[t] = mask[b*KN + t];
    {
        const short8v z8 = {0,0,0,0,0,0,0,0};
        *(short8v*)&xnbT[t][16] = z8;
        *(short8v*)&xnbT[t][24] = z8;
    }

    float xv[16];
    {
        const int cg = m * 16;
        const float* xr = x + (size_t)(b*KN + n)*DM + cg;
        const f32x4 v0 = *(const f32x4*)(xr);
        const f32x4 v1 = *(const f32x4*)(xr + 4);
        const f32x4 v2 = *(const f32x4*)(xr + 8);
        const f32x4 v3 = *(const f32x4*)(xr + 12);
#pragma unroll
        for (int q = 0; q < 4; ++q) { xv[q] = v0[q]; xv[4+q] = v1[q]; xv[8+q] = v2[q]; xv[12+q] = v3[q]; }
        float ssum = 0.f;
#pragma unroll
        for (int q = 0; q < 16; ++q) ssum += xv[q];
#pragma unroll
        for (int o = 1; o < 16; o <<= 1) ssum += __shfl_xor(ssum, o);
        const float mu = ssum * (1.f/DM);
        float vsum = 0.f;
#pragma unroll
        for (int q = 0; q < 16; ++q) { const float d = xv[q]-mu; vsum += d*d; }
#pragma unroll
        for (int o = 1; o < 16; o <<= 1) vsum += __shfl_xor(vsum, o);
        const float rstd = rsqrtf(vsum*(1.f/DM) + 1e-5f);
        const f32x4 ga = *(const f32x4*)(g1 + cg),   gb = *(const f32x4*)(g1 + cg + 4);
        const f32x4 gc = *(const f32x4*)(g1 + cg + 8), gd = *(const f32x4*)(g1 + cg + 12);
        const f32x4 ba = *(const f32x4*)(b1 + cg),   bb = *(const f32x4*)(b1 + cg + 4);
        const f32x4 bc = *(const f32x4*)(b1 + cg + 8), bd = *(const f32x4*)(b1 + cg + 12);
        float gg[16], bbv[16];
#pragma unroll
        for (int q = 0; q < 4; ++q) {
            gg[q] = ga[q]; gg[4+q] = gb[q]; gg[8+q] = gc[q]; gg[12+q] = gd[q];
            bbv[q] = ba[q]; bbv[4+q] = bb[q]; bbv[8+q] = bc[q]; bbv[12+q] = bd[q];
        }
#pragma unroll
        for (int q = 0; q < 16; ++q) {
            xv[q] = (xv[q]-mu)*rstd*gg[q] + bbv[q];
            xnbT[cg + q][n] = f2bf(xv[q]);
        }
    }

    { // P via partials + 4-round butterfly over the 16 m-lanes
        float partc[16];
#pragma unroll
        for (int c = 0; c < 16; ++c) partc[c] = 0.f;
        const int cg = m * 16;
#pragma unroll
        for (int q = 0; q < 16; ++q) {
            const float xq = xv[q];
            const float* wr = Wg + (size_t)(cg + q)*KN;
            const f32x4 w0 = *(const f32x4*)(wr);
            const f32x4 w1 = *(const f32x4*)(wr + 4);
            const f32x4 w2 = *(const f32x4*)(wr + 8);
            const f32x4 w3 = *(const f32x4*)(wr + 12);
            partc[0]  += xq*w0[0]; partc[1]  += xq*w0[1]; partc[2]  += xq*w0[2]; partc[3]  += xq*w0[3];
            partc[4]  += xq*w1[0]; partc[5]  += xq*w1[1]; partc[6]  += xq*w1[2]; partc[7]  += xq*w1[3];
            partc[8]  += xq*w2[0]; partc[9]  += xq*w2[1]; partc[10] += xq*w2[2]; partc[11] += xq*w2[3];
            partc[12] += xq*w3[0]; partc[13] += xq*w3[1]; partc[14] += xq*w3[2]; partc[15] += xq*w3[3];
        }
        const int b0 = t & 1, b1b = (t>>1)&1, b2 = (t>>2)&1, b3 = (t>>3)&1;
        float p8[8];
#pragma unroll
        for (int c2 = 0; c2 < 8; ++c2) {
            const float keep = b0 ? partc[2*c2+1] : partc[2*c2];
            const float send = b0 ? partc[2*c2]   : partc[2*c2+1];
            p8[c2] = keep + __shfl_xor(send, 1);
        }
        float p4[4];
#pragma unroll
        for (int c2 = 0; c2 < 4; ++c2) {
            const float keep = b1b ? p8[2*c2+1] : p8[2*c2];
            const float send = b1b ? p8[2*c2]   : p8[2*c2+1];
            p4[c2] = keep + __shfl_xor(send, 2);
        }
        float p2v[2];
#pragma unroll
        for (int c2 = 0; c2 < 2; ++c2) {
            const float keep = b2 ? p4[2*c2+1] : p4[2*c2];
            const float send = b2 ? p4[2*c2]   : p4[2*c2+1];
            p2v[c2] = keep + __shfl_xor(send, 4);
        }
        const float keep = b3 ? p2v[1] : p2v[0];
        const float send = b3 ? p2v[0] : p2v[1];
        Plds[n][m] = keep + __shfl_xor(send, 8) + bg[m];
    }
    __syncthreads();   // barrier A

    // ---- phase 1: d2 -> sA, T0, HQ; zero Tbf pads ----
    float T0[NS], hq;
    {
        float d2 = 0.f;
#pragma unroll
        for (int k = 0; k < KN; ++k) {
            const float dd = Plds[n][k] - Plds[m][k];
            d2 += dd*dd;
        }
        const float m2v = mskL[n]*mskL[m];
        const float dm = (d2 > 0.f) ? sqrtf(d2)*m2v : 0.f;
        const float dmsq = dm*dm;
        const float adjv = adjL[t];
#pragma unroll
        for (int s = 0; s < NS; ++s) {
            const float sig2 = __expf(2.f*log_scales[s]);
            const float a = __expf(-dmsq/(2.f*sig2 + 1e-8f)) * m2v;
            sA[s][n][m] = a;
            const float am = a * adjv;
            float rsum = am;
#pragma unroll
            for (int o = 1; o < 16; o <<= 1) rsum += __shfl_xor(rsum, o);
            const float tv = (m == n) ? (TAUF + rsum) : (-am);
            T0[s] = tv;
            Tbf[s][n][m] = f2bf(tv);
        }
        hq = 0.f;
#pragma unroll
        for (int k = 0; k < KN; ++k)
            hq += mskL[k]*QL[n*16 + k]*QL[m*16 + k];
#pragma unroll
        for (int idx = 0; idx < 6; ++idx) {
            const int e2 = idx*256 + t;
            Tbf[e2 >> 8][(e2 >> 4) & 15][16 + (e2 & 15)] = 0;
        }
    }
    __syncthreads();   // barrier B

    // ---- phase 2: atomic-free triangle reduction (4 chunks x 3 scales x 16 mids) ----
    {
        const int c4 = t >> 6, rem = t & 63;
        const int midb = rem & 15, sb = rem >> 4;   // sb 0..3
        if (sb < NS) {
            const float* sAf = &sA[sb][0][0];
            float acc = 0.f;
            const int lo = midOff[midb], hi = midOff[midb + 1];
            for (int ii = lo + c4; ii < hi; ii += 4) {
                const int pk = triSrt[ii];
                acc += sAf[pk & 255] * sAf[(pk >> 8) & 255] * sAf[(pk >> 16) & 255];
            }
            part[c4][sb][midb] = 4.f * acc;
        }
    }
    __syncthreads();   // barrier C

    // ---- phase 3: T1, rowsums ----
    {
        float T1[NS];
        const float p2v = P2L[t];
#pragma unroll
        for (int s = 0; s < NS; ++s) {
            float hup = 0.f;
            if (m == n)
                hup = part[0][s][n] + part[1][s][n] + part[2][s][n] + part[3][s][n];
            const float tv = hq + TAUF*p2v + hup;
            T1[s] = tv;
            Tbf[NS + s][n][m] = f2bf(tv);
        }
        float sv[6] = {T0[0], T0[1], T0[2], T1[0], T1[1], T1[2]};
#pragma unroll
        for (int q = 0; q < 6; ++q) {
            float v = sv[q];
#pragma unroll
            for (int o = 1; o < 16; o <<= 1) v += __shfl_xor(v, o);
            sv[q] = v;
        }
        const float wv = (m==0)?sv[0]:(m==1)?sv[1]:(m==2)?sv[2]:(m==3)?sv[3]:(m==4)?sv[4]:sv[5];
        if (m < 6) rstOut[(size_t)b*96 + m*16 + n] = wv;
    }
    __syncthreads();   // barrier D

    // ---- dumps: Tbf (6144 B) + xnT (16384 B), coalesced ----
    {
        const short8v* st = (const short8v*)&Tbf[0][0][0];
        short8v* dt = (short8v*)(tbf + (size_t)b*3072);
        dt[t] = st[t];
        if (t < 128) dt[256 + t] = st[256 + t];
        const short8v* sx = (const short8v*)&xnbT[0][0];
        short8v* dx = (short8v*)(xnt + (size_t)b*8192);
#pragma unroll
        for (int q = 0; q < 4; ++q) dx[q*256 + t] = sx[q*256 + t];
    }
}

// ---------------------------------------------------------------------------
// zmfma kernel: stage Tbf + xnT via global_load_lds, 24 MFMAs -> Z rows,
// plus bias/pad cols (1536..1663). One block per batch.
// ---------------------------------------------------------------------------
__global__ __launch_bounds__(256) void zmfma_kernel(
    const ushort_t* __restrict__ tbf, const ushort_t* __restrict__ xnt,
    const float* __restrict__ rst, ushort_t* __restrict__ Z)
{
    const int b = blockIdx.x, t = threadIdx.x;
    __shared__ ushort_t xnbT[DM][32];
    __shared__ ushort_t Tbf[6][KN][32];
    __shared__ float rs[96];

    const ushort_t* xs = xnt + (size_t)b*8192;
    const ushort_t* ts = tbf + (size_t)b*3072;
#pragma unroll
    for (int q = 0; q < 4; ++q)
        gload_lds16(xs + (size_t)(q*256 + t)*8, ((ushort_t*)xnbT) + (q*256 + t)*8);
    gload_lds16(ts + (size_t)t*8, ((ushort_t*)Tbf) + t*8);
    if (t < 128)
        gload_lds16(ts + (size_t)(256 + t)*8, ((ushort_t*)Tbf) + (256 + t)*8);
    if (t < 96) rs[t] = rst[(size_t)b*96 + t];
    __syncthreads();

    ushort_t* Zb = Z + (size_t)b*KN*KAUG;
    const int w = t >> 6, l = t & 63;
    const int lr = l & 15, lk = l >> 4;
    short8v bfrT[6];
#pragma unroll
    for (int m6 = 0; m6 < 6; ++m6)
        bfrT[m6] = *(const short8v*)&Tbf[m6][lr][lk*8];
#pragma unroll
    for (int q4 = 0; q4 < 4; ++q4) {
        const int jb = w*64 + q4*16;
        const short8v axn = *(const short8v*)&xnbT[jb + lr][lk*8];
#pragma unroll
        for (int m6 = 0; m6 < 6; ++m6) {
            f32x4 acc = {0.f,0.f,0.f,0.f};
            acc = __builtin_amdgcn_mfma_f32_16x16x32_bf16(axn, bfrT[m6], acc, 0, 0, 0);
            short4v zv;
#pragma unroll
            for (int rg = 0; rg < 4; ++rg) zv[rg] = (short)f2bf(acc[rg]);
            *(short4v*)(Zb + (size_t)lr*KAUG + m6*256 + jb + lk*4) = zv;
        }
    }
    // bias + pad cols 1536..1663
    {
        const int row = t >> 4, grp = t & 15;
        short8v tv = {0,0,0,0,0,0,0,0};
        if (grp == 0) {
#pragma unroll
            for (int i = 0; i < 6; ++i) tv[i] = (short)f2bf(rs[i*16 + row]);
        }
        *(short8v*)(Zb + (size_t)row*KAUG + 1536 + grp*8) = tv;
    }
}

// ---------------------------------------------------------------------------
// LDS-staged MFMA GEMM with T2 XOR swizzle.  4 waves (2x2).
// EPI 2: outF += acc + bias     EPI 3: outF = resid + acc + bias
// ---------------------------------------------------------------------------
template<int BM, int BN, int BK, int KD, int EPI>
__global__ __launch_bounds__(256) void gemm_lds(
    const ushort_t* __restrict__ A, const ushort_t* __restrict__ Bt,
    const float* __restrict__ bias, const float* __restrict__ resid,
    float* __restrict__ outF, ushort_t* __restrict__ outH, int ldo)
{
    constexpr int ROWB = BK*2;
    constexpr int KS = BK/32;
    constexpr int MF = BM/32, NF = BN/32;
    constexpr int APASS = BM*ROWB/4096;
    constexpr int BPASS = BN*ROWB/4096;
    __shared__ ushort_t lA[BM*BK];
    __shared__ ushort_t lB[BN*BK];
    const int t = threadIdx.x;
    const int w = t >> 6, l = t & 63;
    const int wm = w & 1, wn = w >> 1;
    const int lr = l & 15, lk = l >> 4;
    const int brow = blockIdx.x * BM;
    const int bcol = blockIdx.y * BN;

    f32x4 acc[MF][NF];
#pragma unroll
    for (int mf = 0; mf < MF; ++mf)
#pragma unroll
        for (int nt = 0; nt < NF; ++nt)
            acc[mf][nt] = (f32x4){0.f,0.f,0.f,0.f};

    const int byteoff = t * 16;

    for (int kc = 0; kc < KD/BK; ++kc) {
        if (kc) __syncthreads();
#pragma unroll
        for (int c = 0; c < APASS; ++c) {
            const int bo = c*4096 + byteoff;
            const int row = bo / ROWB;
            const int gs = ((bo % ROWB) >> 4) ^ (row & 7);
            gload_lds16(A + (size_t)(brow + row)*KD + kc*BK + gs*8, lA + (bo >> 1));
        }
#pragma unroll
        for (int c = 0; c < BPASS; ++c) {
            const int bo = c*4096 + byteoff;
            const int row = bo / ROWB;
            const int gs = ((bo % ROWB) >> 4) ^ (row & 7);
            gload_lds16(Bt + (size_t)(bcol + row)*KD + kc*BK + gs*8, lB + (bo >> 1));
        }
        __syncthreads();
#pragma unroll
        for (int ks = 0; ks < KS; ++ks) {
            short8v af[MF], bfr[NF];
#pragma unroll
            for (int mf = 0; mf < MF; ++mf) {
                const int ra = wm*(BM/2) + mf*16 + lr;
                const int gs = (ks*4 + lk) ^ (ra & 7);
                af[mf] = *(const short8v*)(lA + ra*BK + gs*8);
            }
#pragma unroll
            for (int nt = 0; nt < NF; ++nt) {
                const int rb = wn*(BN/2) + nt*16 + lr;
                const int gs = (ks*4 + lk) ^ (rb & 7);
                bfr[nt] = *(const short8v*)(lB + rb*BK + gs*8);
            }
#pragma unroll
            for (int mf = 0; mf < MF; ++mf)
#pragma unroll
                for (int nt = 0; nt < NF; ++nt)
                    acc[mf][nt] = __builtin_amdgcn_mfma_f32_16x16x32_bf16(
                        af[mf], bfr[nt], acc[mf][nt], 0, 0, 0);
        }
    }

#pragma unroll
    for (int mf = 0; mf < MF; ++mf) {
#pragma unroll
        for (int nt = 0; nt < NF; ++nt) {
            const int col = bcol + wn*(BN/2) + nt*16 + lr;
#pragma unroll
            for (int rg = 0; rg < 4; ++rg) {
                const int row = brow + wm*(BM/2) + mf*16 + lk*4 + rg;
                const size_t o = (size_t)row * ldo + col;
                const float v = acc[mf][nt][rg];
                if (EPI == 2) {
                    outF[o] = outF[o] + v + bias[col];
                } else {
                    outF[o] = resid[o] + v + bias[col];
                }
            }
        }
    }
}

// ---------------------------------------------------------------------------
// FFN1 with fused LN prologue.
// ---------------------------------------------------------------------------
__global__ __launch_bounds__(256) void gemm_ffn1(
    const float* __restrict__ x2, const float* __restrict__ gv,
    const float* __restrict__ bv,
    const ushort_t* __restrict__ Bt, const float* __restrict__ bias,
    ushort_t* __restrict__ outH)
{
    constexpr int BM = 64, BN = 128, KD = 256, BK = 64, ROWB = BK*2;
    __shared__ ushort_t lnA[BM*KD];
    __shared__ ushort_t lB[BN*BK];
    const int t = threadIdx.x;
    const int w = t >> 6, l = t & 63;
    const int wm = w & 1, wn = w >> 1;
    const int lr = l & 15, lk = l >> 4;
    const int brow = blockIdx.x * BM;
    const int bcol = blockIdx.y * BN;

    {
        const int row = t >> 2, c0 = (t & 3) * 64;
        const float* xr = x2 + (size_t)(brow + row)*DM + c0;
        f32x4 va[16];
        float s = 0.f;
#pragma unroll
        for (int q = 0; q < 16; ++q) {
            va[q] = *(const f32x4*)(xr + q*4);
            s += va[q][0] + va[q][1] + va[q][2] + va[q][3];
        }
        s += __shfl_xor(s, 1); s += __shfl_xor(s, 2);
        const float mu = s * (1.f/DM);
        float vs = 0.f;
#pragma unroll
        for (int q = 0; q < 16; ++q) {
#pragma unroll
            for (int i = 0; i < 4; ++i) { const float d = va[q][i]-mu; vs += d*d; }
        }
        vs += __shfl_xor(vs, 1); vs += __shfl_xor(vs, 2);
        const float rstd = rsqrtf(vs*(1.f/DM) + 1e-5f);
#pragma unroll
        for (int q = 0; q < 16; q += 2) {
            short8v o;
#pragma unroll
            for (int i = 0; i < 4; ++i) {
                const int c = c0 + q*4 + i;
                o[i] = (short)f2bf((va[q][i]-mu)*rstd*gv[c] + bv[c]);
            }
#pragma unroll
            for (int i = 0; i < 4; ++i) {
                const int c = c0 + (q+1)*4 + i;
                o[4+i] = (short)f2bf((va[q+1][i]-mu)*rstd*gv[c] + bv[c]);
            }
            const int g = (c0 >> 3) + (q >> 1);
            const int gs = g ^ (row & 7);
            *(short8v*)(lnA + row*KD + gs*8) = o;
        }
    }

    f32x4 acc[2][4];
#pragma unroll
    for (int mf = 0; mf < 2; ++mf)
#pragma unroll
        for (int nt = 0; nt < 4; ++nt)
            acc[mf][nt] = (f32x4){0.f,0.f,0.f,0.f};

    const int byteoff = t * 16;
    for (int kc = 0; kc < KD/BK; ++kc) {
        __syncthreads();
#pragma unroll
        for (int c = 0; c < 4; ++c) {
            const int bo = c*4096 + byteoff;
            const int row = bo / ROWB;
            const int gs = ((bo % ROWB) >> 4) ^ (row & 7);
            gload_lds16(Bt + (size_t)(bcol + row)*KD + kc*BK + gs*8, lB + (bo >> 1));
        }
        __syncthreads();
#pragma unroll
        for (int ks = 0; ks < 2; ++ks) {
            short8v af[2], bfr[4];
#pragma unroll
            for (int mf = 0; mf < 2; ++mf) {
                const int ra = wm*32 + mf*16 + lr;
                const int g = kc*8 + ks*4 + lk;
                const int gs = g ^ (ra & 7);
                af[mf] = *(const short8v*)(lnA + ra*KD + gs*8);
            }
#pragma unroll
            for (int nt = 0; nt < 4; ++nt) {
                const int rb = wn*64 + nt*16 + lr;
                const int gs = (ks*4 + lk) ^ (rb & 7);
                bfr[nt] = *(const short8v*)(lB + rb*BK + gs*8);
            }
#pragma unroll
            for (int mf = 0; mf < 2; ++mf)
#pragma unroll
                for (int nt = 0; nt < 4; ++nt)
                    acc[mf][nt] = __builtin_amdgcn_mfma_f32_16x16x32_bf16(
                        af[mf], bfr[nt], acc[mf][nt], 0, 0, 0);
        }
    }

#pragma unroll
    for (int mf = 0; mf < 2; ++mf) {
#pragma unroll
        for (int nt = 0; nt < 4; ++nt) {
            const int col = bcol + wn*64 + nt*16 + lr;
#pragma unroll
            for (int rg = 0; rg < 4; ++rg) {
                const int row = brow + wm*32 + mf*16 + lk*4 + rg;
                const float u = acc[mf][nt][rg] + bias[col];
                const float a = 0.79788456080286536f*(u + 0.044715f*u*u*u);
                outH[(size_t)row*1024 + col] = f2bf(u / (1.f + __expf(-2.f*a)));
            }
        }
    }
}

extern "C" void kernel_launch(void* const* d_in, const int* in_sizes, int n_in,
                              void* d_out, int out_size, void* d_ws, size_t ws_size,
                              hipStream_t stream) {
    const float* x          = (const float*)d_in[0];
    const float* mask       = (const float*)d_in[1];
    const int*   e_i        = (const int*)  d_in[5];
    const int*   e_j        = (const int*)  d_in[6];
    const int*   t_ij       = (const int*)  d_in[7];
    const int*   t_jk       = (const int*)  d_in[8];
    const int*   t_ik       = (const int*)  d_in[9];
    const float* log_scales = (const float*)d_in[10];
    const float* Wg         = (const float*)d_in[11];
    const float* bg         = (const float*)d_in[12];
    const float* Wv0        = (const float*)d_in[13];
    const float* bv0        = (const float*)d_in[14];
    const float* We         = (const float*)d_in[15];
    const float* be         = (const float*)d_in[16];
    const float* Wout       = (const float*)d_in[17];
    const float* bout       = (const float*)d_in[18];
    const float* g1         = (const float*)d_in[19];
    const float* b1         = (const float*)d_in[20];
    const float* g2         = (const float*)d_in[21];
    const float* b2         = (const float*)d_in[22];
    const float* Wf1        = (const float*)d_in[23];
    const float* bf1        = (const float*)d_in[24];
    const float* Wf2        = (const float*)d_in[25];
    const float* bf2        = (const float*)d_in[26];

    char* wsb = (char*)d_ws;
    ushort_t* wstack = (ushort_t*)(wsb + OFF_WSTACK);
    ushort_t* wf1t   = (ushort_t*)(wsb + OFF_WF1T);
    ushort_t* wf2t   = (ushort_t*)(wsb + OFF_WF2T);
    float*    topoF  = (float*)   (wsb + OFF_TOPO);
    int*      midOff = (int*)     (wsb + OFF_TOPO + 3072);
    int*      triSrt = (int*)     (wsb + OFF_TOPO + 3200);
    float*    rst    = (float*)   (wsb + OFF_RST);
    ushort_t* tbf    = (ushort_t*)(wsb + OFF_TBF);
    ushort_t* xnt    = (ushort_t*)(wsb + OFF_XNT);
    ushort_t* Z      = (ushort_t*)(wsb + OFF_Z);
    ushort_t* H      = (ushort_t*)(wsb + OFF_H);
    float*    out    = (float*)d_out;

    // 1. weight prep + topology tables
    hipLaunchKernelGGL(prep_kernel, dim3(231), dim3(256), 0, stream,
                       Wv0, bv0, We, be, Wout, Wf1, Wf2,
                       e_i, e_j, t_ij, t_jk, t_ik,
                       wstack, wf1t, wf2t, topoF, midOff, triSrt);
    // 2. topology -> Tbf, xnT, rowsums
    hipLaunchKernelGGL(topo_kernel, dim3(NBATCH), dim3(256), 0, stream,
                       x, mask, log_scales, Wg, bg, g1, b1,
                       topoF, midOff, triSrt, tbf, xnt, rst);
    // 3. Z = T @ xn (+bias/pad cols)
    hipLaunchKernelGGL(zmfma_kernel, dim3(NBATCH), dim3(256), 0, stream,
                       tbf, xnt, rst, Z);
    // 4. x2 = x + Z @ Wstack + bout   (M=8192, K=1664, N=256) -> d_out
    hipLaunchKernelGGL((gemm_lds<64,64,128,KAUG,3>), dim3(128,4), dim3(256), 0, stream,
                       Z, wstack, bout, x, out, (ushort_t*)nullptr, 256);
    // 5. H = gelu(LN(x2) @ Wf1 + bf1)
    hipLaunchKernelGGL(gemm_ffn1, dim3(128,8), dim3(256), 0, stream,
                       out, g2, b2, wf1t, bf1, H);
    // 6. out += H @ Wf2 + bf2
    hipLaunchKernelGGL((gemm_lds<64,64,128,1024,2>), dim3(128,4), dim3(256), 0, stream,
                       H, wf2t, bf2, (const float*)nullptr,
                       out, (ushort_t*)nullptr, 256);
}

// Round 9
// 139.703 us; speedup vs baseline: 2.0869x; 2.0869x over previous
//
#include <hip/hip_runtime.h>
#include <math.h>

#define KN 16
#define DM 256
#define NS 3
#define NE 120
#define NT_TRI 560
#define NBATCH 512
#define TAUF 1e-4f
#define KAUG 1664            // 1536 + 6 bias cols + 122 zero pad (13*128)

typedef unsigned short ushort_t;
typedef __attribute__((ext_vector_type(8))) short short8v;
typedef __attribute__((ext_vector_type(4))) short short4v;
typedef __attribute__((ext_vector_type(4))) float f32x4;

// ---- workspace byte offsets (~39 MB total) ----
#define OFF_WSTACK 0u          // bf16 [256][1664]                       851968
#define OFF_WF1T   851968u     // bf16 [1024][256]                       524288
#define OFF_WF2T   1376256u    // bf16 [256][1024]                       524288
#define OFF_TOPO   1900544u    // f32 Q/P2/adj[768]; midOff[17]; triSrt[560]
#define OFF_RST    1908736u    // f32 [512][96]                         196608
#define OFF_TBF    2105344u    // bf16 [512][6][16][32]                3145728
#define OFF_XNT    5251072u    // bf16 [512][256][32]                  8388608
#define OFF_Z      13639680u   // bf16 [8192][1664]                   27262976
#define OFF_H      13639680u   // bf16 [8192][1024] aliases Z

__device__ __forceinline__ ushort_t f2bf(float f) {
    union { float f; unsigned int u; } v; v.f = f;
    unsigned int r = v.u + 0x7FFFu + ((v.u >> 16) & 1u);
    return (ushort_t)(r >> 16);
}
__device__ __forceinline__ void gload_lds16(const void* g, void* l) {
    auto gp = (const __attribute__((address_space(1))) unsigned int*)(unsigned long long)(g);
    auto lp = (__attribute__((address_space(3))) unsigned int*)(unsigned long long)(l);
    __builtin_amdgcn_global_load_lds(gp, lp, 16, 0, 0);
}

// ---------------------------------------------------------------------------
// Prep: bid<102 fuse Wv0/We x Wout -> Wstack ; bid<166 T(Wf1) ; bid<230 T(Wf2)
//       bid==230 topology tables (parallel, LDS-staged, deterministic)
// ---------------------------------------------------------------------------
__global__ __launch_bounds__(256) void prep_kernel(
    const float* __restrict__ Wv0, const float* __restrict__ bv0,
    const float* __restrict__ We,  const float* __restrict__ be,
    const float* __restrict__ Wout,
    const float* __restrict__ Wf1, const float* __restrict__ Wf2,
    const int* __restrict__ e_i, const int* __restrict__ e_j,
    const int* __restrict__ t_ij, const int* __restrict__ t_jk, const int* __restrict__ t_ik,
    ushort_t* __restrict__ wstack, ushort_t* __restrict__ wf1t,
    ushort_t* __restrict__ wf2t,
    float* __restrict__ topoF, int* __restrict__ midOff, int* __restrict__ triSrt)
{
    __shared__ float lhs[16][DM];
    __shared__ float tile[64][65];
    __shared__ int   eidxL[256];
    __shared__ int   eiL[NE], ejL[NE];
    __shared__ int   midL[NT_TRI], pkL[NT_TRI];
    __shared__ int   cnts[16], offs[17];
    const int bid = blockIdx.x;
    const int j = threadIdx.x;

    if (bid == 230) {   // topology tables — fully parallel via LDS staging
        eidxL[j] = -1;
        if (j < NE) { eiL[j] = e_i[j]; ejL[j] = e_j[j]; }
        __syncthreads();
        if (j < NE) {
            eidxL[eiL[j]*16 + ejL[j]] = j;
            eidxL[ejL[j]*16 + eiL[j]] = j;
        }
        __syncthreads();
        const int n = j >> 4, m = j & 15;
        float q, p2, adj;
        if (n != m) {
            const int e = eidxL[j];
            if (e >= 0) { q = (m == ejL[e]) ? 1.f : -1.f; p2 = 1.f; adj = 1.f; }
            else        { q = 0.f; p2 = 0.f; adj = 0.f; }
        } else {
            q = 0.f; p2 = 0.f; adj = 0.f;
            for (int kk = 0; kk < KN; ++kk) {
                if (kk == n) continue;
                const int e = eidxL[n*16 + kk];
                if (e >= 0) { q += (n == ejL[e]) ? 1.f : -1.f; p2 += 1.f; }
            }
        }
        topoF[j] = q; topoF[256 + j] = p2; topoF[512 + j] = adj;

        // coalesced triangle load + pack into LDS
        for (int tt = j; tt < NT_TRI; tt += 256) {
            const int eij = t_ij[tt], ejk = t_jk[tt], eik = t_ik[tt];
            const int a0 = eiL[eij], a1 = ejL[eij];
            const int b0 = eiL[ejk], b1v = ejL[ejk];
            const int c0 = eiL[eik], c1 = ejL[eik];
            const int mid = (b0 == a0 || b0 == a1) ? b0 : b1v;
            midL[tt] = mid;
            pkL[tt]  = (a0*16 + a1) | ((b0*16 + b1v) << 8) | ((c0*16 + c1) << 16);
        }
        __syncthreads();
        if (j < 16) {      // bucket counts from LDS (broadcast reads)
            int c = 0;
            for (int tt = 0; tt < NT_TRI; ++tt) c += (midL[tt] == j);
            cnts[j] = c;
        }
        __syncthreads();
        if (j == 0) {
            int s = 0;
            for (int q2 = 0; q2 < 16; ++q2) { offs[q2] = s; s += cnts[q2]; }
            offs[16] = s;
        }
        __syncthreads();
        if (j < 17) midOff[j] = offs[j];
        // deterministic stable scatter: rank = #earlier triangles with same mid
        for (int tt = j; tt < NT_TRI; tt += 256) {
            const int mid = midL[tt];
            int r = 0;
            for (int q2 = 0; q2 < NT_TRI; ++q2)
                r += (q2 < tt && midL[q2] == mid);
            triSrt[offs[mid] + r] = pkL[tt];
        }
        return;
    }

    if (bid < 102) {
        const int m = bid / 17, by = bid % 17;
        const int path = m / 3, s = m % 3;
        const float* __restrict__ Wo = Wout + (size_t)m*DM*DM;
        if (by == 16) {   // fused bias -> K-row 1536+m ; zero pad K-rows
            const float* bv = (path == 0) ? bv0 : be;
            const float f = (path == 0) ? 1.0f : 0.5f;   // 1_E = 0.5*|B1|^T 1_K
            float acc = 0.f;
            for (int k = 0; k < DM; ++k)
                acc += bv[s*DM + k] * f * Wo[k*DM + j];
            wstack[(size_t)j*KAUG + 1536 + m] = f2bf(acc);
            if (m == 0)
                for (int c = 1542; c < KAUG; ++c)
                    wstack[(size_t)j*KAUG + c] = 0;
            return;
        }
        const float* src = (path == 0) ? Wv0 : We;
        const int i0 = by * 16;
        for (int r = 0; r < 16; ++r)
            lhs[r][j] = src[(size_t)(i0 + r)*(NS*DM) + s*DM + j];
        __syncthreads();
        float acc[16];
#pragma unroll
        for (int r = 0; r < 16; ++r) acc[r] = 0.f;
        for (int k = 0; k < DM; ++k) {
            const float w = Wo[k*DM + j];
#pragma unroll
            for (int r = 0; r < 16; ++r) acc[r] += lhs[r][k] * w;
        }
#pragma unroll
        for (int r = 0; r < 16; ++r)
            wstack[(size_t)j*KAUG + m*DM + i0 + r] = f2bf(acc[r]);
        return;
    }

    // transpose branches
    const float* in; ushort_t* outp; int R, C, rt, ct;
    if (bid < 166) {
        const int q = bid - 102;
        in = Wf1; outp = wf1t; R = 256; C = 1024;
        rt = (q >> 4) * 64; ct = (q & 15) * 64;
    } else {
        const int q = bid - 166;
        in = Wf2; outp = wf2t; R = 1024; C = 256;
        rt = (q >> 2) * 64; ct = (q & 3) * 64;
    }
#pragma unroll
    for (int q2 = 0; q2 < 16; ++q2) {
        const int idx = q2*256 + j;
        const int r = idx >> 6, c = idx & 63;
        tile[r][c] = in[(size_t)(rt + r)*C + ct + c];
    }
    __syncthreads();
#pragma unroll
    for (int q2 = 0; q2 < 16; ++q2) {
        const int idx = q2*256 + j;
        const int cc = idx >> 6, rr = idx & 63;
        outp[(size_t)(ct + cc)*R + rt + rr] = f2bf(tile[rr][cc]);
    }
}

// ---------------------------------------------------------------------------
// Topo kernel: LN -> P -> A_s -> T (atomic-free tri pass). Dumps Tbf, xnT,
// rowsums to workspace. One block per batch.
// ---------------------------------------------------------------------------
__global__ __launch_bounds__(256) void topo_kernel(
    const float* __restrict__ x, const float* __restrict__ mask,
    const float* __restrict__ log_scales,
    const float* __restrict__ Wg, const float* __restrict__ bg,
    const float* __restrict__ g1, const float* __restrict__ b1,
    const float* __restrict__ topoF, const int* __restrict__ midOff,
    const int* __restrict__ triSrt,
    ushort_t* __restrict__ tbf, ushort_t* __restrict__ xnt,
    float* __restrict__ rstOut)
{
    const int b = blockIdx.x;
    const int t = threadIdx.x;
    const int n = t >> 4, m = t & 15;

    __shared__ ushort_t xnbT[DM][32];    // xn^T [col][node], cols 16..31 = 0 (16 KB)
    __shared__ float Plds[KN][KN];
    __shared__ float mskL[KN];
    __shared__ float QL[256];
    __shared__ float P2L[256];
    __shared__ float adjL[256];
    __shared__ float sA[NS][KN][KN];
    __shared__ float part[4][NS][KN];
    __shared__ ushort_t Tbf[6][KN][32];  // K padded to 32, 6 KB

    // ---- phase 0: tables, mask, LN, P ----
    QL[t]  = topoF[t];
    P2L[t] = topoF[256 + t];
    adjL[t] = topoF[512 + t];
    if (t < KN) mskL[t] = mask[b*KN + t];
    {
        const short8v z8 = {0,0,0,0,0,0,0,0};
        *(short8v*)&xnbT[t][16] = z8;
        *(short8v*)&xnbT[t][24] = z8;
    }

    float xv[16];
    {
        const int cg = m * 16;
        const float* xr = x + (size_t)(b*KN + n)*DM + cg;
        const f32x4 v0 = *(const f32x4*)(xr);
        const f32x4 v1 = *(const f32x4*)(xr + 4);
        const f32x4 v2 = *(const f32x4*)(xr + 8);
        const f32x4 v3 = *(const f32x4*)(xr + 12);
#pragma unroll
        for (int q = 0; q < 4; ++q) { xv[q] = v0[q]; xv[4+q] = v1[q]; xv[8+q] = v2[q]; xv[12+q] = v3[q]; }
        float ssum = 0.f;
#pragma unroll
        for (int q = 0; q < 16; ++q) ssum += xv[q];
#pragma unroll
        for (int o = 1; o < 16; o <<= 1) ssum += __shfl_xor(ssum, o);
        const float mu = ssum * (1.f/DM);
        float vsum = 0.f;
#pragma unroll
        for (int q = 0; q < 16; ++q) { const float d = xv[q]-mu; vsum += d*d; }
#pragma unroll
        for (int o = 1; o < 16; o <<= 1) vsum += __shfl_xor(vsum, o);
        const float rstd = rsqrtf(vsum*(1.f/DM) + 1e-5f);
        const f32x4 ga = *(const f32x4*)(g1 + cg),   gb = *(const f32x4*)(g1 + cg + 4);
        const f32x4 gc = *(const f32x4*)(g1 + cg + 8), gd = *(const f32x4*)(g1 + cg + 12);
        const f32x4 ba = *(const f32x4*)(b1 + cg),   bb = *(const f32x4*)(b1 + cg + 4);
        const f32x4 bc = *(const f32x4*)(b1 + cg + 8), bd = *(const f32x4*)(b1 + cg + 12);
        float gg[16], bbv[16];
#pragma unroll
        for (int q = 0; q < 4; ++q) {
            gg[q] = ga[q]; gg[4+q] = gb[q]; gg[8+q] = gc[q]; gg[12+q] = gd[q];
            bbv[q] = ba[q]; bbv[4+q] = bb[q]; bbv[8+q] = bc[q]; bbv[12+q] = bd[q];
        }
#pragma unroll
        for (int q = 0; q < 16; ++q) {
            xv[q] = (xv[q]-mu)*rstd*gg[q] + bbv[q];
            xnbT[cg + q][n] = f2bf(xv[q]);
        }
    }

    { // P via partials + 4-round butterfly over the 16 m-lanes
        float partc[16];
#pragma unroll
        for (int c = 0; c < 16; ++c) partc[c] = 0.f;
        const int cg = m * 16;
#pragma unroll
        for (int q = 0; q < 16; ++q) {
            const float xq = xv[q];
            const float* wr = Wg + (size_t)(cg + q)*KN;
            const f32x4 w0 = *(const f32x4*)(wr);
            const f32x4 w1 = *(const f32x4*)(wr + 4);
            const f32x4 w2 = *(const f32x4*)(wr + 8);
            const f32x4 w3 = *(const f32x4*)(wr + 12);
            partc[0]  += xq*w0[0]; partc[1]  += xq*w0[1]; partc[2]  += xq*w0[2]; partc[3]  += xq*w0[3];
            partc[4]  += xq*w1[0]; partc[5]  += xq*w1[1]; partc[6]  += xq*w1[2]; partc[7]  += xq*w1[3];
            partc[8]  += xq*w2[0]; partc[9]  += xq*w2[1]; partc[10] += xq*w2[2]; partc[11] += xq*w2[3];
            partc[12] += xq*w3[0]; partc[13] += xq*w3[1]; partc[14] += xq*w3[2]; partc[15] += xq*w3[3];
        }
        const int b0 = t & 1, b1b = (t>>1)&1, b2 = (t>>2)&1, b3 = (t>>3)&1;
        float p8[8];
#pragma unroll
        for (int c2 = 0; c2 < 8; ++c2) {
            const float keep = b0 ? partc[2*c2+1] : partc[2*c2];
            const float send = b0 ? partc[2*c2]   : partc[2*c2+1];
            p8[c2] = keep + __shfl_xor(send, 1);
        }
        float p4[4];
#pragma unroll
        for (int c2 = 0; c2 < 4; ++c2) {
            const float keep = b1b ? p8[2*c2+1] : p8[2*c2];
            const float send = b1b ? p8[2*c2]   : p8[2*c2+1];
            p4[c2] = keep + __shfl_xor(send, 2);
        }
        float p2v[2];
#pragma unroll
        for (int c2 = 0; c2 < 2; ++c2) {
            const float keep = b2 ? p4[2*c2+1] : p4[2*c2];
            const float send = b2 ? p4[2*c2]   : p4[2*c2+1];
            p2v[c2] = keep + __shfl_xor(send, 4);
        }
        const float keep = b3 ? p2v[1] : p2v[0];
        const float send = b3 ? p2v[0] : p2v[1];
        Plds[n][m] = keep + __shfl_xor(send, 8) + bg[m];
    }
    __syncthreads();   // barrier A

    // ---- phase 1: d2 -> sA, T0, HQ; zero Tbf pads ----
    float T0[NS], hq;
    {
        float d2 = 0.f;
#pragma unroll
        for (int k = 0; k < KN; ++k) {
            const float dd = Plds[n][k] - Plds[m][k];
            d2 += dd*dd;
        }
        const float m2v = mskL[n]*mskL[m];
        const float dm = (d2 > 0.f) ? sqrtf(d2)*m2v : 0.f;
        const float dmsq = dm*dm;
        const float adjv = adjL[t];
#pragma unroll
        for (int s = 0; s < NS; ++s) {
            const float sig2 = __expf(2.f*log_scales[s]);
            const float a = __expf(-dmsq/(2.f*sig2 + 1e-8f)) * m2v;
            sA[s][n][m] = a;
            const float am = a * adjv;
            float rsum = am;
#pragma unroll
            for (int o = 1; o < 16; o <<= 1) rsum += __shfl_xor(rsum, o);
            const float tv = (m == n) ? (TAUF + rsum) : (-am);
            T0[s] = tv;
            Tbf[s][n][m] = f2bf(tv);
        }
        hq = 0.f;
#pragma unroll
        for (int k = 0; k < KN; ++k)
            hq += mskL[k]*QL[n*16 + k]*QL[m*16 + k];
#pragma unroll
        for (int idx = 0; idx < 6; ++idx) {
            const int e2 = idx*256 + t;
            Tbf[e2 >> 8][(e2 >> 4) & 15][16 + (e2 & 15)] = 0;
        }
    }
    __syncthreads();   // barrier B

    // ---- phase 2: atomic-free triangle reduction (4 chunks x 3 scales x 16 mids) ----
    {
        const int c4 = t >> 6, rem = t & 63;
        const int midb = rem & 15, sb = rem >> 4;   // sb 0..3
        if (sb < NS) {
            const float* sAf = &sA[sb][0][0];
            float acc = 0.f;
            const int lo = midOff[midb], hi = midOff[midb + 1];
            for (int ii = lo + c4; ii < hi; ii += 4) {
                const int pk = triSrt[ii];
                acc += sAf[pk & 255] * sAf[(pk >> 8) & 255] * sAf[(pk >> 16) & 255];
            }
            part[c4][sb][midb] = 4.f * acc;
        }
    }
    __syncthreads();   // barrier C

    // ---- phase 3: T1, rowsums ----
    {
        float T1[NS];
        const float p2v = P2L[t];
#pragma unroll
        for (int s = 0; s < NS; ++s) {
            float hup = 0.f;
            if (m == n)
                hup = part[0][s][n] + part[1][s][n] + part[2][s][n] + part[3][s][n];
            const float tv = hq + TAUF*p2v + hup;
            T1[s] = tv;
            Tbf[NS + s][n][m] = f2bf(tv);
        }
        float sv[6] = {T0[0], T0[1], T0[2], T1[0], T1[1], T1[2]};
#pragma unroll
        for (int q = 0; q < 6; ++q) {
            float v = sv[q];
#pragma unroll
            for (int o = 1; o < 16; o <<= 1) v += __shfl_xor(v, o);
            sv[q] = v;
        }
        const float wv = (m==0)?sv[0]:(m==1)?sv[1]:(m==2)?sv[2]:(m==3)?sv[3]:(m==4)?sv[4]:sv[5];
        if (m < 6) rstOut[(size_t)b*96 + m*16 + n] = wv;
    }
    __syncthreads();   // barrier D

    // ---- dumps: Tbf (6144 B) + xnT (16384 B), coalesced ----
    {
        const short8v* st = (const short8v*)&Tbf[0][0][0];
        short8v* dt = (short8v*)(tbf + (size_t)b*3072);
        dt[t] = st[t];
        if (t < 128) dt[256 + t] = st[256 + t];
        const short8v* sx = (const short8v*)&xnbT[0][0];
        short8v* dx = (short8v*)(xnt + (size_t)b*8192);
#pragma unroll
        for (int q = 0; q < 4; ++q) dx[q*256 + t] = sx[q*256 + t];
    }
}

// ---------------------------------------------------------------------------
// zmfma kernel: stage Tbf + xnT via global_load_lds, 24 MFMAs -> Z rows,
// plus bias/pad cols (1536..1663). One block per batch.
// ---------------------------------------------------------------------------
__global__ __launch_bounds__(256) void zmfma_kernel(
    const ushort_t* __restrict__ tbf, const ushort_t* __restrict__ xnt,
    const float* __restrict__ rst, ushort_t* __restrict__ Z)
{
    const int b = blockIdx.x, t = threadIdx.x;
    __shared__ ushort_t xnbT[DM][32];
    __shared__ ushort_t Tbf[6][KN][32];
    __shared__ float rs[96];

    const ushort_t* xs = xnt + (size_t)b*8192;
    const ushort_t* ts = tbf + (size_t)b*3072;
#pragma unroll
    for (int q = 0; q < 4; ++q)
        gload_lds16(xs + (size_t)(q*256 + t)*8, ((ushort_t*)xnbT) + (q*256 + t)*8);
    gload_lds16(ts + (size_t)t*8, ((ushort_t*)Tbf) + t*8);
    if (t < 128)
        gload_lds16(ts + (size_t)(256 + t)*8, ((ushort_t*)Tbf) + (256 + t)*8);
    if (t < 96) rs[t] = rst[(size_t)b*96 + t];
    __syncthreads();

    ushort_t* Zb = Z + (size_t)b*KN*KAUG;
    const int w = t >> 6, l = t & 63;
    const int lr = l & 15, lk = l >> 4;
    short8v bfrT[6];
#pragma unroll
    for (int m6 = 0; m6 < 6; ++m6)
        bfrT[m6] = *(const short8v*)&Tbf[m6][lr][lk*8];
#pragma unroll
    for (int q4 = 0; q4 < 4; ++q4) {
        const int jb = w*64 + q4*16;
        const short8v axn = *(const short8v*)&xnbT[jb + lr][lk*8];
#pragma unroll
        for (int m6 = 0; m6 < 6; ++m6) {
            f32x4 acc = {0.f,0.f,0.f,0.f};
            acc = __builtin_amdgcn_mfma_f32_16x16x32_bf16(axn, bfrT[m6], acc, 0, 0, 0);
            short4v zv;
#pragma unroll
            for (int rg = 0; rg < 4; ++rg) zv[rg] = (short)f2bf(acc[rg]);
            *(short4v*)(Zb + (size_t)lr*KAUG + m6*256 + jb + lk*4) = zv;
        }
    }
    // bias + pad cols 1536..1663
    {
        const int row = t >> 4, grp = t & 15;
        short8v tv = {0,0,0,0,0,0,0,0};
        if (grp == 0) {
#pragma unroll
            for (int i = 0; i < 6; ++i) tv[i] = (short)f2bf(rs[i*16 + row]);
        }
        *(short8v*)(Zb + (size_t)row*KAUG + 1536 + grp*8) = tv;
    }
}

// ---------------------------------------------------------------------------
// LDS-staged MFMA GEMM with T2 XOR swizzle.  4 waves (2x2).
// EPI 2: outF += acc + bias     EPI 3: outF = resid + acc + bias
// ---------------------------------------------------------------------------
template<int BM, int BN, int BK, int KD, int EPI>
__global__ __launch_bounds__(256) void gemm_lds(
    const ushort_t* __restrict__ A, const ushort_t* __restrict__ Bt,
    const float* __restrict__ bias, const float* __restrict__ resid,
    float* __restrict__ outF, ushort_t* __restrict__ outH, int ldo)
{
    constexpr int ROWB = BK*2;
    constexpr int KS = BK/32;
    constexpr int MF = BM/32, NF = BN/32;
    constexpr int APASS = BM*ROWB/4096;
    constexpr int BPASS = BN*ROWB/4096;
    __shared__ ushort_t lA[BM*BK];
    __shared__ ushort_t lB[BN*BK];
    const int t = threadIdx.x;
    const int w = t >> 6, l = t & 63;
    const int wm = w & 1, wn = w >> 1;
    const int lr = l & 15, lk = l >> 4;
    const int brow = blockIdx.x * BM;
    const int bcol = blockIdx.y * BN;

    f32x4 acc[MF][NF];
#pragma unroll
    for (int mf = 0; mf < MF; ++mf)
#pragma unroll
        for (int nt = 0; nt < NF; ++nt)
            acc[mf][nt] = (f32x4){0.f,0.f,0.f,0.f};

    const int byteoff = t * 16;

    for (int kc = 0; kc < KD/BK; ++kc) {
        if (kc) __syncthreads();
#pragma unroll
        for (int c = 0; c < APASS; ++c) {
            const int bo = c*4096 + byteoff;
            const int row = bo / ROWB;
            const int gs = ((bo % ROWB) >> 4) ^ (row & 7);
            gload_lds16(A + (size_t)(brow + row)*KD + kc*BK + gs*8, lA + (bo >> 1));
        }
#pragma unroll
        for (int c = 0; c < BPASS; ++c) {
            const int bo = c*4096 + byteoff;
            const int row = bo / ROWB;
            const int gs = ((bo % ROWB) >> 4) ^ (row & 7);
            gload_lds16(Bt + (size_t)(bcol + row)*KD + kc*BK + gs*8, lB + (bo >> 1));
        }
        __syncthreads();
#pragma unroll
        for (int ks = 0; ks < KS; ++ks) {
            short8v af[MF], bfr[NF];
#pragma unroll
            for (int mf = 0; mf < MF; ++mf) {
                const int ra = wm*(BM/2) + mf*16 + lr;
                const int gs = (ks*4 + lk) ^ (ra & 7);
                af[mf] = *(const short8v*)(lA + ra*BK + gs*8);
            }
#pragma unroll
            for (int nt = 0; nt < NF; ++nt) {
                const int rb = wn*(BN/2) + nt*16 + lr;
                const int gs = (ks*4 + lk) ^ (rb & 7);
                bfr[nt] = *(const short8v*)(lB + rb*BK + gs*8);
            }
#pragma unroll
            for (int mf = 0; mf < MF; ++mf)
#pragma unroll
                for (int nt = 0; nt < NF; ++nt)
                    acc[mf][nt] = __builtin_amdgcn_mfma_f32_16x16x32_bf16(
                        af[mf], bfr[nt], acc[mf][nt], 0, 0, 0);
        }
    }

#pragma unroll
    for (int mf = 0; mf < MF; ++mf) {
#pragma unroll
        for (int nt = 0; nt < NF; ++nt) {
            const int col = bcol + wn*(BN/2) + nt*16 + lr;
#pragma unroll
            for (int rg = 0; rg < 4; ++rg) {
                const int row = brow + wm*(BM/2) + mf*16 + lk*4 + rg;
                const size_t o = (size_t)row * ldo + col;
                const float v = acc[mf][nt][rg];
                if (EPI == 2) {
                    outF[o] = outF[o] + v + bias[col];
                } else {
                    outF[o] = resid[o] + v + bias[col];
                }
            }
        }
    }
}

// ---------------------------------------------------------------------------
// FFN1 with fused LN prologue.
// ---------------------------------------------------------------------------
__global__ __launch_bounds__(256) void gemm_ffn1(
    const float* __restrict__ x2, const float* __restrict__ gv,
    const float* __restrict__ bv,
    const ushort_t* __restrict__ Bt, const float* __restrict__ bias,
    ushort_t* __restrict__ outH)
{
    constexpr int BM = 64, BN = 128, KD = 256, BK = 64, ROWB = BK*2;
    __shared__ ushort_t lnA[BM*KD];
    __shared__ ushort_t lB[BN*BK];
    const int t = threadIdx.x;
    const int w = t >> 6, l = t & 63;
    const int wm = w & 1, wn = w >> 1;
    const int lr = l & 15, lk = l >> 4;
    const int brow = blockIdx.x * BM;
    const int bcol = blockIdx.y * BN;

    {
        const int row = t >> 2, c0 = (t & 3) * 64;
        const float* xr = x2 + (size_t)(brow + row)*DM + c0;
        f32x4 va[16];
        float s = 0.f;
#pragma unroll
        for (int q = 0; q < 16; ++q) {
            va[q] = *(const f32x4*)(xr + q*4);
            s += va[q][0] + va[q][1] + va[q][2] + va[q][3];
        }
        s += __shfl_xor(s, 1); s += __shfl_xor(s, 2);
        const float mu = s * (1.f/DM);
        float vs = 0.f;
#pragma unroll
        for (int q = 0; q < 16; ++q) {
#pragma unroll
            for (int i = 0; i < 4; ++i) { const float d = va[q][i]-mu; vs += d*d; }
        }
        vs += __shfl_xor(vs, 1); vs += __shfl_xor(vs, 2);
        const float rstd = rsqrtf(vs*(1.f/DM) + 1e-5f);
#pragma unroll
        for (int q = 0; q < 16; q += 2) {
            short8v o;
#pragma unroll
            for (int i = 0; i < 4; ++i) {
                const int c = c0 + q*4 + i;
                o[i] = (short)f2bf((va[q][i]-mu)*rstd*gv[c] + bv[c]);
            }
#pragma unroll
            for (int i = 0; i < 4; ++i) {
                const int c = c0 + (q+1)*4 + i;
                o[4+i] = (short)f2bf((va[q+1][i]-mu)*rstd*gv[c] + bv[c]);
            }
            const int g = (c0 >> 3) + (q >> 1);
            const int gs = g ^ (row & 7);
            *(short8v*)(lnA + row*KD + gs*8) = o;
        }
    }

    f32x4 acc[2][4];
#pragma unroll
    for (int mf = 0; mf < 2; ++mf)
#pragma unroll
        for (int nt = 0; nt < 4; ++nt)
            acc[mf][nt] = (f32x4){0.f,0.f,0.f,0.f};

    const int byteoff = t * 16;
    for (int kc = 0; kc < KD/BK; ++kc) {
        __syncthreads();
#pragma unroll
        for (int c = 0; c < 4; ++c) {
            const int bo = c*4096 + byteoff;
            const int row = bo / ROWB;
            const int gs = ((bo % ROWB) >> 4) ^ (row & 7);
            gload_lds16(Bt + (size_t)(bcol + row)*KD + kc*BK + gs*8, lB + (bo >> 1));
        }
        __syncthreads();
#pragma unroll
        for (int ks = 0; ks < 2; ++ks) {
            short8v af[2], bfr[4];
#pragma unroll
            for (int mf = 0; mf < 2; ++mf) {
                const int ra = wm*32 + mf*16 + lr;
                const int g = kc*8 + ks*4 + lk;
                const int gs = g ^ (ra & 7);
                af[mf] = *(const short8v*)(lnA + ra*KD + gs*8);
            }
#pragma unroll
            for (int nt = 0; nt < 4; ++nt) {
                const int rb = wn*64 + nt*16 + lr;
                const int gs = (ks*4 + lk) ^ (rb & 7);
                bfr[nt] = *(const short8v*)(lB + rb*BK + gs*8);
            }
#pragma unroll
            for (int mf = 0; mf < 2; ++mf)
#pragma unroll
                for (int nt = 0; nt < 4; ++nt)
                    acc[mf][nt] = __builtin_amdgcn_mfma_f32_16x16x32_bf16(
                        af[mf], bfr[nt], acc[mf][nt], 0, 0, 0);
        }
    }

#pragma unroll
    for (int mf = 0; mf < 2; ++mf) {
#pragma unroll
        for (int nt = 0; nt < 4; ++nt) {
            const int col = bcol + wn*64 + nt*16 + lr;
#pragma unroll
            for (int rg = 0; rg < 4; ++rg) {
                const int row = brow + wm*32 + mf*16 + lk*4 + rg;
                const float u = acc[mf][nt][rg] + bias[col];
                const float a = 0.79788456080286536f*(u + 0.044715f*u*u*u);
                outH[(size_t)row*1024 + col] = f2bf(u / (1.f + __expf(-2.f*a)));
            }
        }
    }
}

extern "C" void kernel_launch(void* const* d_in, const int* in_sizes, int n_in,
                              void* d_out, int out_size, void* d_ws, size_t ws_size,
                              hipStream_t stream) {
    const float* x          = (const float*)d_in[0];
    const float* mask       = (const float*)d_in[1];
    const int*   e_i        = (const int*)  d_in[5];
    const int*   e_j        = (const int*)  d_in[6];
    const int*   t_ij       = (const int*)  d_in[7];
    const int*   t_jk       = (const int*)  d_in[8];
    const int*   t_ik       = (const int*)  d_in[9];
    const float* log_scales = (const float*)d_in[10];
    const float* Wg         = (const float*)d_in[11];
    const float* bg         = (const float*)d_in[12];
    const float* Wv0        = (const float*)d_in[13];
    const float* bv0        = (const float*)d_in[14];
    const float* We         = (const float*)d_in[15];
    const float* be         = (const float*)d_in[16];
    const float* Wout       = (const float*)d_in[17];
    const float* bout       = (const float*)d_in[18];
    const float* g1         = (const float*)d_in[19];
    const float* b1         = (const float*)d_in[20];
    const float* g2         = (const float*)d_in[21];
    const float* b2         = (const float*)d_in[22];
    const float* Wf1        = (const float*)d_in[23];
    const float* bf1        = (const float*)d_in[24];
    const float* Wf2        = (const float*)d_in[25];
    const float* bf2        = (const float*)d_in[26];

    char* wsb = (char*)d_ws;
    ushort_t* wstack = (ushort_t*)(wsb + OFF_WSTACK);
    ushort_t* wf1t   = (ushort_t*)(wsb + OFF_WF1T);
    ushort_t* wf2t   = (ushort_t*)(wsb + OFF_WF2T);
    float*    topoF  = (float*)   (wsb + OFF_TOPO);
    int*      midOff = (int*)     (wsb + OFF_TOPO + 3072);
    int*      triSrt = (int*)     (wsb + OFF_TOPO + 3200);
    float*    rst    = (float*)   (wsb + OFF_RST);
    ushort_t* tbf    = (ushort_t*)(wsb + OFF_TBF);
    ushort_t* xnt    = (ushort_t*)(wsb + OFF_XNT);
    ushort_t* Z      = (ushort_t*)(wsb + OFF_Z);
    ushort_t* H      = (ushort_t*)(wsb + OFF_H);
    float*    out    = (float*)d_out;

    // 1. weight prep + topology tables
    hipLaunchKernelGGL(prep_kernel, dim3(231), dim3(256), 0, stream,
                       Wv0, bv0, We, be, Wout, Wf1, Wf2,
                       e_i, e_j, t_ij, t_jk, t_ik,
                       wstack, wf1t, wf2t, topoF, midOff, triSrt);
    // 2. topology -> Tbf, xnT, rowsums
    hipLaunchKernelGGL(topo_kernel, dim3(NBATCH), dim3(256), 0, stream,
                       x, mask, log_scales, Wg, bg, g1, b1,
                       topoF, midOff, triSrt, tbf, xnt, rst);
    // 3. Z = T @ xn (+bias/pad cols)
    hipLaunchKernelGGL(zmfma_kernel, dim3(NBATCH), dim3(256), 0, stream,
                       tbf, xnt, rst, Z);
    // 4. x2 = x + Z @ Wstack + bout   (M=8192, K=1664, N=256) -> d_out
    hipLaunchKernelGGL((gemm_lds<64,64,128,KAUG,3>), dim3(128,4), dim3(256), 0, stream,
                       Z, wstack, bout, x, out, (ushort_t*)nullptr, 256);
    // 5. H = gelu(LN(x2) @ Wf1 + bf1)
    hipLaunchKernelGGL(gemm_ffn1, dim3(128,8), dim3(256), 0, stream,
                       out, g2, b2, wf1t, bf1, H);
    // 6. out += H @ Wf2 + bf2
    hipLaunchKernelGGL((gemm_lds<64,64,128,1024,2>), dim3(128,4), dim3(256), 0, stream,
                       H, wf2t, bf2, (const float*)nullptr,
                       out, (ushort_t*)nullptr, 256);
}

// Round 10
// 131.130 us; speedup vs baseline: 2.2233x; 1.0654x over previous
//
#include <hip/hip_runtime.h>
#include <math.h>

#define KN 16
#define DM 256
#define NS 3
#define NE 120
#define NT_TRI 560
#define NBATCH 512
#define TAUF 1e-4f
#define KAUG 1664            // 1536 + 6 bias cols + 122 zero pad (13*128)
#define ZPITCH 1672          // Zstage LDS row pitch (2-way bank conflicts max)

typedef unsigned short ushort_t;
typedef __attribute__((ext_vector_type(8))) short short8v;
typedef __attribute__((ext_vector_type(4))) short short4v;
typedef __attribute__((ext_vector_type(4))) float f32x4;

// ---- workspace byte offsets ----
#define OFF_WSTACK 0u          // bf16 [256][1664]                       851968
#define OFF_WF1T   851968u     // bf16 [1024][256]                       524288
#define OFF_WF2T   1376256u    // bf16 [256][1024]                       524288
#define OFF_TOPO   1900544u    // f32 Q/P2/adj[768]; midOff[17]; triSrt[560]
#define OFF_Z      1908736u    // bf16 [8192][1664]                   27262976
#define OFF_H      1908736u    // bf16 [8192][1024] aliases Z

__device__ __forceinline__ ushort_t f2bf(float f) {
    union { float f; unsigned int u; } v; v.f = f;
    unsigned int r = v.u + 0x7FFFu + ((v.u >> 16) & 1u);
    return (ushort_t)(r >> 16);
}
__device__ __forceinline__ void gload_lds16(const void* g, void* l) {
    auto gp = (const __attribute__((address_space(1))) unsigned int*)(unsigned long long)(g);
    auto lp = (__attribute__((address_space(3))) unsigned int*)(unsigned long long)(l);
    __builtin_amdgcn_global_load_lds(gp, lp, 16, 0, 0);
}

// ---------------------------------------------------------------------------
// Prep: bid<102 fuse Wv0/We x Wout -> Wstack ; bid<166 T(Wf1) ; bid<230 T(Wf2)
//       bid==230 topology tables (parallel, LDS-staged, deterministic)
// ---------------------------------------------------------------------------
__global__ __launch_bounds__(256) void prep_kernel(
    const float* __restrict__ Wv0, const float* __restrict__ bv0,
    const float* __restrict__ We,  const float* __restrict__ be,
    const float* __restrict__ Wout,
    const float* __restrict__ Wf1, const float* __restrict__ Wf2,
    const int* __restrict__ e_i, const int* __restrict__ e_j,
    const int* __restrict__ t_ij, const int* __restrict__ t_jk, const int* __restrict__ t_ik,
    ushort_t* __restrict__ wstack, ushort_t* __restrict__ wf1t,
    ushort_t* __restrict__ wf2t,
    float* __restrict__ topoF, int* __restrict__ midOff, int* __restrict__ triSrt)
{
    __shared__ float lhs[16][DM];
    __shared__ float tile[64][65];
    __shared__ int   eidxL[256];
    __shared__ int   eiL[NE], ejL[NE];
    __shared__ int   midL[NT_TRI], pkL[NT_TRI];
    __shared__ int   cnts[16], offs[17];
    const int bid = blockIdx.x;
    const int j = threadIdx.x;

    if (bid == 230) {
        eidxL[j] = -1;
        if (j < NE) { eiL[j] = e_i[j]; ejL[j] = e_j[j]; }
        __syncthreads();
        if (j < NE) {
            eidxL[eiL[j]*16 + ejL[j]] = j;
            eidxL[ejL[j]*16 + eiL[j]] = j;
        }
        __syncthreads();
        const int n = j >> 4, m = j & 15;
        float q, p2, adj;
        if (n != m) {
            const int e = eidxL[j];
            if (e >= 0) { q = (m == ejL[e]) ? 1.f : -1.f; p2 = 1.f; adj = 1.f; }
            else        { q = 0.f; p2 = 0.f; adj = 0.f; }
        } else {
            q = 0.f; p2 = 0.f; adj = 0.f;
            for (int kk = 0; kk < KN; ++kk) {
                if (kk == n) continue;
                const int e = eidxL[n*16 + kk];
                if (e >= 0) { q += (n == ejL[e]) ? 1.f : -1.f; p2 += 1.f; }
            }
        }
        topoF[j] = q; topoF[256 + j] = p2; topoF[512 + j] = adj;

        for (int tt = j; tt < NT_TRI; tt += 256) {
            const int eij = t_ij[tt], ejk = t_jk[tt], eik = t_ik[tt];
            const int a0 = eiL[eij], a1 = ejL[eij];
            const int b0 = eiL[ejk], b1v = ejL[ejk];
            const int c0 = eiL[eik], c1 = ejL[eik];
            const int mid = (b0 == a0 || b0 == a1) ? b0 : b1v;
            midL[tt] = mid;
            pkL[tt]  = (a0*16 + a1) | ((b0*16 + b1v) << 8) | ((c0*16 + c1) << 16);
        }
        __syncthreads();
        if (j < 16) {
            int c = 0;
            for (int tt = 0; tt < NT_TRI; ++tt) c += (midL[tt] == j);
            cnts[j] = c;
        }
        __syncthreads();
        if (j == 0) {
            int s = 0;
            for (int q2 = 0; q2 < 16; ++q2) { offs[q2] = s; s += cnts[q2]; }
            offs[16] = s;
        }
        __syncthreads();
        if (j < 17) midOff[j] = offs[j];
        for (int tt = j; tt < NT_TRI; tt += 256) {
            const int mid = midL[tt];
            int r = 0;
            for (int q2 = 0; q2 < NT_TRI; ++q2)
                r += (q2 < tt && midL[q2] == mid);
            triSrt[offs[mid] + r] = pkL[tt];
        }
        return;
    }

    if (bid < 102) {
        const int m = bid / 17, by = bid % 17;
        const int path = m / 3, s = m % 3;
        const float* __restrict__ Wo = Wout + (size_t)m*DM*DM;
        if (by == 16) {
            const float* bv = (path == 0) ? bv0 : be;
            const float f = (path == 0) ? 1.0f : 0.5f;   // 1_E = 0.5*|B1|^T 1_K
            float acc = 0.f;
            for (int k = 0; k < DM; ++k)
                acc += bv[s*DM + k] * f * Wo[k*DM + j];
            wstack[(size_t)j*KAUG + 1536 + m] = f2bf(acc);
            if (m == 0)
                for (int c = 1542; c < KAUG; ++c)
                    wstack[(size_t)j*KAUG + c] = 0;
            return;
        }
        const float* src = (path == 0) ? Wv0 : We;
        const int i0 = by * 16;
        for (int r = 0; r < 16; ++r)
            lhs[r][j] = src[(size_t)(i0 + r)*(NS*DM) + s*DM + j];
        __syncthreads();
        float acc[16];
#pragma unroll
        for (int r = 0; r < 16; ++r) acc[r] = 0.f;
        for (int k = 0; k < DM; ++k) {
            const float w = Wo[k*DM + j];
#pragma unroll
            for (int r = 0; r < 16; ++r) acc[r] += lhs[r][k] * w;
        }
#pragma unroll
        for (int r = 0; r < 16; ++r)
            wstack[(size_t)j*KAUG + m*DM + i0 + r] = f2bf(acc[r]);
        return;
    }

    const float* in; ushort_t* outp; int R, C, rt, ct;
    if (bid < 166) {
        const int q = bid - 102;
        in = Wf1; outp = wf1t; R = 256; C = 1024;
        rt = (q >> 4) * 64; ct = (q & 15) * 64;
    } else {
        const int q = bid - 166;
        in = Wf2; outp = wf2t; R = 1024; C = 256;
        rt = (q >> 2) * 64; ct = (q & 3) * 64;
    }
#pragma unroll
    for (int q2 = 0; q2 < 16; ++q2) {
        const int idx = q2*256 + j;
        const int r = idx >> 6, c = idx & 63;
        tile[r][c] = in[(size_t)(rt + r)*C + ct + c];
    }
    __syncthreads();
#pragma unroll
    for (int q2 = 0; q2 < 16; ++q2) {
        const int idx = q2*256 + j;
        const int cc = idx >> 6, rr = idx & 63;
        outp[(size_t)(ct + cc)*R + rt + rr] = f2bf(tile[rr][cc]);
    }
}

// ---------------------------------------------------------------------------
// Merged topo+Z kernel: LN -> P -> A_s -> T (all-LDS tri pass) -> MFMA into
// LDS Zstage -> coalesced copy-out (incl. bias/pad cols). One block per batch.
// ---------------------------------------------------------------------------
__global__ __launch_bounds__(256) void topoz_kernel(
    const float* __restrict__ x, const float* __restrict__ mask,
    const float* __restrict__ log_scales,
    const float* __restrict__ Wg, const float* __restrict__ bg,
    const float* __restrict__ g1, const float* __restrict__ b1,
    const float* __restrict__ topoF, const int* __restrict__ midOff,
    const int* __restrict__ triSrt,
    ushort_t* __restrict__ Z)
{
    const int b = blockIdx.x;
    const int t = threadIdx.x;
    const int n = t >> 4, m = t & 15;

    __shared__ ushort_t xnbT[DM][16];        // xn^T [col][node], 8 KB
    __shared__ ushort_t Tbf[6][KN][16];      // 3 KB
    __shared__ ushort_t Zstage[KN][ZPITCH];  // 53.5 KB
    __shared__ float    Plds[KN][KN];        // 1 KB (reused as part[] later)
    __shared__ float    sA[NS][KN*KN];       // 3 KB
    __shared__ float    mskL[KN];
    __shared__ int      triL[NT_TRI];        // 2.2 KB
    float (*part)[NS][KN] = (float(*)[NS][KN])&Plds[0][0];  // 192 floats, overlays Plds

    // ---- phase 0: mask, triangle table -> LDS, zero Zstage pad cols, LN, P ----
    if (t < KN) mskL[t] = mask[b*KN + t];
    for (int idx = t; idx < NT_TRI; idx += 256) triL[idx] = triSrt[idx];
    {
        const short8v z8 = {0,0,0,0,0,0,0,0};
        for (int i2 = t; i2 < 16*17; i2 += 256) {       // cols 1536..1671
            const int row = i2 / 17, ch = i2 % 17;
            *(short8v*)&Zstage[row][1536 + ch*8] = z8;
        }
    }

    float xv[16];
    {
        const int cg = m * 16;
        const float* xr = x + (size_t)(b*KN + n)*DM + cg;
        const f32x4 v0 = *(const f32x4*)(xr);
        const f32x4 v1 = *(const f32x4*)(xr + 4);
        const f32x4 v2 = *(const f32x4*)(xr + 8);
        const f32x4 v3 = *(const f32x4*)(xr + 12);
#pragma unroll
        for (int q = 0; q < 4; ++q) { xv[q] = v0[q]; xv[4+q] = v1[q]; xv[8+q] = v2[q]; xv[12+q] = v3[q]; }
        float ssum = 0.f;
#pragma unroll
        for (int q = 0; q < 16; ++q) ssum += xv[q];
#pragma unroll
        for (int o = 1; o < 16; o <<= 1) ssum += __shfl_xor(ssum, o);
        const float mu = ssum * (1.f/DM);
        float vsum = 0.f;
#pragma unroll
        for (int q = 0; q < 16; ++q) { const float d = xv[q]-mu; vsum += d*d; }
#pragma unroll
        for (int o = 1; o < 16; o <<= 1) vsum += __shfl_xor(vsum, o);
        const float rstd = rsqrtf(vsum*(1.f/DM) + 1e-5f);
        const f32x4 ga = *(const f32x4*)(g1 + cg),   gb = *(const f32x4*)(g1 + cg + 4);
        const f32x4 gc = *(const f32x4*)(g1 + cg + 8), gd = *(const f32x4*)(g1 + cg + 12);
        const f32x4 ba = *(const f32x4*)(b1 + cg),   bb = *(const f32x4*)(b1 + cg + 4);
        const f32x4 bc = *(const f32x4*)(b1 + cg + 8), bd = *(const f32x4*)(b1 + cg + 12);
        float gg[16], bbv[16];
#pragma unroll
        for (int q = 0; q < 4; ++q) {
            gg[q] = ga[q]; gg[4+q] = gb[q]; gg[8+q] = gc[q]; gg[12+q] = gd[q];
            bbv[q] = ba[q]; bbv[4+q] = bb[q]; bbv[8+q] = bc[q]; bbv[12+q] = bd[q];
        }
#pragma unroll
        for (int q = 0; q < 16; ++q) {
            xv[q] = (xv[q]-mu)*rstd*gg[q] + bbv[q];
            xnbT[cg + q][n] = f2bf(xv[q]);
        }
    }

    { // P via partials + 4-round butterfly over the 16 m-lanes
        float partc[16];
#pragma unroll
        for (int c = 0; c < 16; ++c) partc[c] = 0.f;
        const int cg = m * 16;
#pragma unroll
        for (int q = 0; q < 16; ++q) {
            const float xq = xv[q];
            const float* wr = Wg + (size_t)(cg + q)*KN;
            const f32x4 w0 = *(const f32x4*)(wr);
            const f32x4 w1 = *(const f32x4*)(wr + 4);
            const f32x4 w2 = *(const f32x4*)(wr + 8);
            const f32x4 w3 = *(const f32x4*)(wr + 12);
            partc[0]  += xq*w0[0]; partc[1]  += xq*w0[1]; partc[2]  += xq*w0[2]; partc[3]  += xq*w0[3];
            partc[4]  += xq*w1[0]; partc[5]  += xq*w1[1]; partc[6]  += xq*w1[2]; partc[7]  += xq*w1[3];
            partc[8]  += xq*w2[0]; partc[9]  += xq*w2[1]; partc[10] += xq*w2[2]; partc[11] += xq*w2[3];
            partc[12] += xq*w3[0]; partc[13] += xq*w3[1]; partc[14] += xq*w3[2]; partc[15] += xq*w3[3];
        }
        const int b0 = t & 1, b1b = (t>>1)&1, b2 = (t>>2)&1, b3 = (t>>3)&1;
        float p8[8];
#pragma unroll
        for (int c2 = 0; c2 < 8; ++c2) {
            const float keep = b0 ? partc[2*c2+1] : partc[2*c2];
            const float send = b0 ? partc[2*c2]   : partc[2*c2+1];
            p8[c2] = keep + __shfl_xor(send, 1);
        }
        float p4[4];
#pragma unroll
        for (int c2 = 0; c2 < 4; ++c2) {
            const float keep = b1b ? p8[2*c2+1] : p8[2*c2];
            const float send = b1b ? p8[2*c2]   : p8[2*c2+1];
            p4[c2] = keep + __shfl_xor(send, 2);
        }
        float p2v[2];
#pragma unroll
        for (int c2 = 0; c2 < 2; ++c2) {
            const float keep = b2 ? p4[2*c2+1] : p4[2*c2];
            const float send = b2 ? p4[2*c2]   : p4[2*c2+1];
            p2v[c2] = keep + __shfl_xor(send, 4);
        }
        const float keep = b3 ? p2v[1] : p2v[0];
        const float send = b3 ? p2v[0] : p2v[1];
        Plds[n][m] = keep + __shfl_xor(send, 8) + bg[m];
    }
    __syncthreads();   // barrier A

    // ---- phase 1: d2 -> sA, T0, HQ ----
    float T0[NS], hq;
    {
        float d2 = 0.f;
#pragma unroll
        for (int k = 0; k < KN; ++k) {
            const float dd = Plds[n][k] - Plds[m][k];
            d2 += dd*dd;
        }
        const float m2v = mskL[n]*mskL[m];
        const float dm = (d2 > 0.f) ? sqrtf(d2)*m2v : 0.f;
        const float dmsq = dm*dm;
        const float adjv = topoF[512 + t];
#pragma unroll
        for (int s = 0; s < NS; ++s) {
            const float sig2 = __expf(2.f*log_scales[s]);
            const float a = __expf(-dmsq/(2.f*sig2 + 1e-8f)) * m2v;
            sA[s][t] = a;
            const float am = a * adjv;
            float rsum = am;
#pragma unroll
            for (int o = 1; o < 16; o <<= 1) rsum += __shfl_xor(rsum, o);
            const float tv = (m == n) ? (TAUF + rsum) : (-am);
            T0[s] = tv;
            Tbf[s][n][m] = f2bf(tv);
        }
        hq = 0.f;
#pragma unroll
        for (int k = 0; k < KN; ++k)
            hq += mskL[k]*topoF[n*16 + k]*topoF[m*16 + k];
    }
    __syncthreads();   // barrier B  (Plds dead; part[] takes over its LDS)

    // ---- phase 2: atomic-free triangle reduction, all-LDS ----
    {
        const int c4 = t >> 6, rem = t & 63;
        const int midb = rem & 15, sb = rem >> 4;
        if (sb < NS) {
            const float* sAf = &sA[sb][0];
            float acc = 0.f;
            const int lo = midOff[midb], hi = midOff[midb + 1];
            for (int ii = lo + c4; ii < hi; ii += 4) {
                const int pk = triL[ii];
                acc += sAf[pk & 255] * sAf[(pk >> 8) & 255] * sAf[(pk >> 16) & 255];
            }
            part[c4][sb][midb] = 4.f * acc;
        }
    }
    __syncthreads();   // barrier C

    // ---- phase 3: T1, rowsums -> Zstage bias cols ----
    {
        float T1[NS];
        const float p2v = topoF[256 + t];
#pragma unroll
        for (int s = 0; s < NS; ++s) {
            float hup = 0.f;
            if (m == n)
                hup = part[0][s][n] + part[1][s][n] + part[2][s][n] + part[3][s][n];
            const float tv = hq + TAUF*p2v + hup;
            T1[s] = tv;
            Tbf[NS + s][n][m] = f2bf(tv);
        }
        float sv[6] = {T0[0], T0[1], T0[2], T1[0], T1[1], T1[2]};
#pragma unroll
        for (int q = 0; q < 6; ++q) {
            float v = sv[q];
#pragma unroll
            for (int o = 1; o < 16; o <<= 1) v += __shfl_xor(v, o);
            sv[q] = v;
        }
        const float wv = (m==0)?sv[0]:(m==1)?sv[1]:(m==2)?sv[2]:(m==3)?sv[3]:(m==4)?sv[4]:sv[5];
        if (m < 6) Zstage[n][1536 + m] = f2bf(wv);
    }
    __syncthreads();   // barrier D

    // ---- phase 4: MFMA (K=16 padded to 32 via register-zero frags) -> Zstage ----
    {
        const int w = t >> 6, l = t & 63;
        const int lr = l & 15, lk = l >> 4;
        const short8v z8 = {0,0,0,0,0,0,0,0};
        short8v bfrT[6];
#pragma unroll
        for (int m6 = 0; m6 < 6; ++m6)
            bfrT[m6] = (lk < 2) ? *(const short8v*)&Tbf[m6][lr][lk*8] : z8;
#pragma unroll
        for (int q4 = 0; q4 < 4; ++q4) {
            const int jb = w*64 + q4*16;
            const short8v axn = (lk < 2) ? *(const short8v*)&xnbT[jb + lr][lk*8] : z8;
#pragma unroll
            for (int m6 = 0; m6 < 6; ++m6) {
                f32x4 acc = {0.f,0.f,0.f,0.f};
                acc = __builtin_amdgcn_mfma_f32_16x16x32_bf16(axn, bfrT[m6], acc, 0, 0, 0);
                short4v zv;
#pragma unroll
                for (int rg = 0; rg < 4; ++rg) zv[rg] = (short)f2bf(acc[rg]);
                *(short4v*)&Zstage[lr][m6*256 + jb + lk*4] = zv;
            }
        }
    }
    __syncthreads();   // barrier E

    // ---- phase 5: coalesced copy-out (16 rows x 3328 B) ----
    {
        ushort_t* Zb = Z + (size_t)b*KN*KAUG;
#pragma unroll
        for (int i = 0; i < 13; ++i) {
            const int cid = t + 256*i;          // 0..3327
            const int row = cid / 208;
            const int off = (cid % 208) * 8;
            *(short8v*)(Zb + (size_t)row*KAUG + off) = *(const short8v*)&Zstage[row][off];
        }
    }
}

// ---------------------------------------------------------------------------
// LDS-staged MFMA GEMM with T2 XOR swizzle.  4 waves (2x2).
// EPI 2: outF += acc + bias     EPI 3: outF = resid + acc + bias
// ---------------------------------------------------------------------------
template<int BM, int BN, int BK, int KD, int EPI>
__global__ __launch_bounds__(256) void gemm_lds(
    const ushort_t* __restrict__ A, const ushort_t* __restrict__ Bt,
    const float* __restrict__ bias, const float* __restrict__ resid,
    float* __restrict__ outF, ushort_t* __restrict__ outH, int ldo)
{
    constexpr int ROWB = BK*2;
    constexpr int KS = BK/32;
    constexpr int MF = BM/32, NF = BN/32;
    constexpr int APASS = BM*ROWB/4096;
    constexpr int BPASS = BN*ROWB/4096;
    __shared__ ushort_t lA[BM*BK];
    __shared__ ushort_t lB[BN*BK];
    const int t = threadIdx.x;
    const int w = t >> 6, l = t & 63;
    const int wm = w & 1, wn = w >> 1;
    const int lr = l & 15, lk = l >> 4;
    const int brow = blockIdx.x * BM;
    const int bcol = blockIdx.y * BN;

    f32x4 acc[MF][NF];
#pragma unroll
    for (int mf = 0; mf < MF; ++mf)
#pragma unroll
        for (int nt = 0; nt < NF; ++nt)
            acc[mf][nt] = (f32x4){0.f,0.f,0.f,0.f};

    const int byteoff = t * 16;

    for (int kc = 0; kc < KD/BK; ++kc) {
        if (kc) __syncthreads();
#pragma unroll
        for (int c = 0; c < APASS; ++c) {
            const int bo = c*4096 + byteoff;
            const int row = bo / ROWB;
            const int gs = ((bo % ROWB) >> 4) ^ (row & 7);
            gload_lds16(A + (size_t)(brow + row)*KD + kc*BK + gs*8, lA + (bo >> 1));
        }
#pragma unroll
        for (int c = 0; c < BPASS; ++c) {
            const int bo = c*4096 + byteoff;
            const int row = bo / ROWB;
            const int gs = ((bo % ROWB) >> 4) ^ (row & 7);
            gload_lds16(Bt + (size_t)(bcol + row)*KD + kc*BK + gs*8, lB + (bo >> 1));
        }
        __syncthreads();
#pragma unroll
        for (int ks = 0; ks < KS; ++ks) {
            short8v af[MF], bfr[NF];
#pragma unroll
            for (int mf = 0; mf < MF; ++mf) {
                const int ra = wm*(BM/2) + mf*16 + lr;
                const int gs = (ks*4 + lk) ^ (ra & 7);
                af[mf] = *(const short8v*)(lA + ra*BK + gs*8);
            }
#pragma unroll
            for (int nt = 0; nt < NF; ++nt) {
                const int rb = wn*(BN/2) + nt*16 + lr;
                const int gs = (ks*4 + lk) ^ (rb & 7);
                bfr[nt] = *(const short8v*)(lB + rb*BK + gs*8);
            }
#pragma unroll
            for (int mf = 0; mf < MF; ++mf)
#pragma unroll
                for (int nt = 0; nt < NF; ++nt)
                    acc[mf][nt] = __builtin_amdgcn_mfma_f32_16x16x32_bf16(
                        af[mf], bfr[nt], acc[mf][nt], 0, 0, 0);
        }
    }

#pragma unroll
    for (int mf = 0; mf < MF; ++mf) {
#pragma unroll
        for (int nt = 0; nt < NF; ++nt) {
            const int col = bcol + wn*(BN/2) + nt*16 + lr;
#pragma unroll
            for (int rg = 0; rg < 4; ++rg) {
                const int row = brow + wm*(BM/2) + mf*16 + lk*4 + rg;
                const size_t o = (size_t)row * ldo + col;
                const float v = acc[mf][nt][rg];
                if (EPI == 2) {
                    outF[o] = outF[o] + v + bias[col];
                } else {
                    outF[o] = resid[o] + v + bias[col];
                }
            }
        }
    }
}

// ---------------------------------------------------------------------------
// FFN1 with fused LN prologue.
// ---------------------------------------------------------------------------
__global__ __launch_bounds__(256) void gemm_ffn1(
    const float* __restrict__ x2, const float* __restrict__ gv,
    const float* __restrict__ bv,
    const ushort_t* __restrict__ Bt, const float* __restrict__ bias,
    ushort_t* __restrict__ outH)
{
    constexpr int BM = 64, BN = 128, KD = 256, BK = 64, ROWB = BK*2;
    __shared__ ushort_t lnA[BM*KD];
    __shared__ ushort_t lB[BN*BK];
    const int t = threadIdx.x;
    const int w = t >> 6, l = t & 63;
    const int wm = w & 1, wn = w >> 1;
    const int lr = l & 15, lk = l >> 4;
    const int brow = blockIdx.x * BM;
    const int bcol = blockIdx.y * BN;

    {
        const int row = t >> 2, c0 = (t & 3) * 64;
        const float* xr = x2 + (size_t)(brow + row)*DM + c0;
        f32x4 va[16];
        float s = 0.f;
#pragma unroll
        for (int q = 0; q < 16; ++q) {
            va[q] = *(const f32x4*)(xr + q*4);
            s += va[q][0] + va[q][1] + va[q][2] + va[q][3];
        }
        s += __shfl_xor(s, 1); s += __shfl_xor(s, 2);
        const float mu = s * (1.f/DM);
        float vs = 0.f;
#pragma unroll
        for (int q = 0; q < 16; ++q) {
#pragma unroll
            for (int i = 0; i < 4; ++i) { const float d = va[q][i]-mu; vs += d*d; }
        }
        vs += __shfl_xor(vs, 1); vs += __shfl_xor(vs, 2);
        const float rstd = rsqrtf(vs*(1.f/DM) + 1e-5f);
#pragma unroll
        for (int q = 0; q < 16; q += 2) {
            short8v o;
#pragma unroll
            for (int i = 0; i < 4; ++i) {
                const int c = c0 + q*4 + i;
                o[i] = (short)f2bf((va[q][i]-mu)*rstd*gv[c] + bv[c]);
            }
#pragma unroll
            for (int i = 0; i < 4; ++i) {
                const int c = c0 + (q+1)*4 + i;
                o[4+i] = (short)f2bf((va[q+1][i]-mu)*rstd*gv[c] + bv[c]);
            }
            const int g = (c0 >> 3) + (q >> 1);
            const int gs = g ^ (row & 7);
            *(short8v*)(lnA + row*KD + gs*8) = o;
        }
    }

    f32x4 acc[2][4];
#pragma unroll
    for (int mf = 0; mf < 2; ++mf)
#pragma unroll
        for (int nt = 0; nt < 4; ++nt)
            acc[mf][nt] = (f32x4){0.f,0.f,0.f,0.f};

    const int byteoff = t * 16;
    for (int kc = 0; kc < KD/BK; ++kc) {
        __syncthreads();
#pragma unroll
        for (int c = 0; c < 4; ++c) {
            const int bo = c*4096 + byteoff;
            const int row = bo / ROWB;
            const int gs = ((bo % ROWB) >> 4) ^ (row & 7);
            gload_lds16(Bt + (size_t)(bcol + row)*KD + kc*BK + gs*8, lB + (bo >> 1));
        }
        __syncthreads();
#pragma unroll
        for (int ks = 0; ks < 2; ++ks) {
            short8v af[2], bfr[4];
#pragma unroll
            for (int mf = 0; mf < 2; ++mf) {
                const int ra = wm*32 + mf*16 + lr;
                const int g = kc*8 + ks*4 + lk;
                const int gs = g ^ (ra & 7);
                af[mf] = *(const short8v*)(lnA + ra*KD + gs*8);
            }
#pragma unroll
            for (int nt = 0; nt < 4; ++nt) {
                const int rb = wn*64 + nt*16 + lr;
                const int gs = (ks*4 + lk) ^ (rb & 7);
                bfr[nt] = *(const short8v*)(lB + rb*BK + gs*8);
            }
#pragma unroll
            for (int mf = 0; mf < 2; ++mf)
#pragma unroll
                for (int nt = 0; nt < 4; ++nt)
                    acc[mf][nt] = __builtin_amdgcn_mfma_f32_16x16x32_bf16(
                        af[mf], bfr[nt], acc[mf][nt], 0, 0, 0);
        }
    }

#pragma unroll
    for (int mf = 0; mf < 2; ++mf) {
#pragma unroll
        for (int nt = 0; nt < 4; ++nt) {
            const int col = bcol + wn*64 + nt*16 + lr;
#pragma unroll
            for (int rg = 0; rg < 4; ++rg) {
                const int row = brow + wm*32 + mf*16 + lk*4 + rg;
                const float u = acc[mf][nt][rg] + bias[col];
                const float a = 0.79788456080286536f*(u + 0.044715f*u*u*u);
                outH[(size_t)row*1024 + col] = f2bf(u / (1.f + __expf(-2.f*a)));
            }
        }
    }
}

extern "C" void kernel_launch(void* const* d_in, const int* in_sizes, int n_in,
                              void* d_out, int out_size, void* d_ws, size_t ws_size,
                              hipStream_t stream) {
    const float* x          = (const float*)d_in[0];
    const float* mask       = (const float*)d_in[1];
    const int*   e_i        = (const int*)  d_in[5];
    const int*   e_j        = (const int*)  d_in[6];
    const int*   t_ij       = (const int*)  d_in[7];
    const int*   t_jk       = (const int*)  d_in[8];
    const int*   t_ik       = (const int*)  d_in[9];
    const float* log_scales = (const float*)d_in[10];
    const float* Wg         = (const float*)d_in[11];
    const float* bg         = (const float*)d_in[12];
    const float* Wv0        = (const float*)d_in[13];
    const float* bv0        = (const float*)d_in[14];
    const float* We         = (const float*)d_in[15];
    const float* be         = (const float*)d_in[16];
    const float* Wout       = (const float*)d_in[17];
    const float* bout       = (const float*)d_in[18];
    const float* g1         = (const float*)d_in[19];
    const float* b1         = (const float*)d_in[20];
    const float* g2         = (const float*)d_in[21];
    const float* b2         = (const float*)d_in[22];
    const float* Wf1        = (const float*)d_in[23];
    const float* bf1        = (const float*)d_in[24];
    const float* Wf2        = (const float*)d_in[25];
    const float* bf2        = (const float*)d_in[26];

    char* wsb = (char*)d_ws;
    ushort_t* wstack = (ushort_t*)(wsb + OFF_WSTACK);
    ushort_t* wf1t   = (ushort_t*)(wsb + OFF_WF1T);
    ushort_t* wf2t   = (ushort_t*)(wsb + OFF_WF2T);
    float*    topoF  = (float*)   (wsb + OFF_TOPO);
    int*      midOff = (int*)     (wsb + OFF_TOPO + 3072);
    int*      triSrt = (int*)     (wsb + OFF_TOPO + 3200);
    ushort_t* Z      = (ushort_t*)(wsb + OFF_Z);
    ushort_t* H      = (ushort_t*)(wsb + OFF_H);
    float*    out    = (float*)d_out;

    // 1. weight prep + topology tables
    hipLaunchKernelGGL(prep_kernel, dim3(231), dim3(256), 0, stream,
                       Wv0, bv0, We, be, Wout, Wf1, Wf2,
                       e_i, e_j, t_ij, t_jk, t_ik,
                       wstack, wf1t, wf2t, topoF, midOff, triSrt);
    // 2. topology -> Z (merged, LDS-staged coalesced store)
    hipLaunchKernelGGL(topoz_kernel, dim3(NBATCH), dim3(256), 0, stream,
                       x, mask, log_scales, Wg, bg, g1, b1,
                       topoF, midOff, triSrt, Z);
    // 3. x2 = x + Z @ Wstack + bout   (M=8192, K=1664, N=256) -> d_out
    hipLaunchKernelGGL((gemm_lds<64,64,128,KAUG,3>), dim3(128,4), dim3(256), 0, stream,
                       Z, wstack, bout, x, out, (ushort_t*)nullptr, 256);
    // 4. H = gelu(LN(x2) @ Wf1 + bf1)
    hipLaunchKernelGGL(gemm_ffn1, dim3(128,8), dim3(256), 0, stream,
                       out, g2, b2, wf1t, bf1, H);
    // 5. out += H @ Wf2 + bf2
    hipLaunchKernelGGL((gemm_lds<64,64,128,1024,2>), dim3(128,4), dim3(256), 0, stream,
                       H, wf2t, bf2, (const float*)nullptr,
                       out, (ushort_t*)nullptr, 256);
}